// Round 16
// baseline (700.093 us; speedup 1.0000x reference)
//
#include <hip/hip_runtime.h>
#include <hip/hip_bf16.h>

#define DEV static __device__ __forceinline__

// ---- static dims ----
#define B_    16
#define Y_    10
#define M_    12
#define WIN_  48
#define T_    5760     // Y*M*WIN
#define DENC_ 256
#define U_    128
#define A1_   64
#define A2_   32
#define K_    8
#define RNN_  256
#define FDEC_ 64
#define NOUT_ 64

#define H1_   45
#define W1_   125
#define H2_   42
#define W2_   122
#define FLATM_ 40992   // H2*W2*K
#define HY_   537
#define WY_   122
#define FLATY_ 524112  // HY*WY*K
#define NSM_  1920     // B*Y*M
#define NSY_  160      // B*Y

typedef __attribute__((ext_vector_type(8))) short s16x8;
typedef __attribute__((ext_vector_type(4))) short s16x4;
typedef __attribute__((ext_vector_type(4))) float f32x4;

DEV float tanh_fast(float x){
  x = fminf(fmaxf(x, -15.0f), 15.0f);
  float e = __expf(2.0f*x);
  return (e - 1.0f) / (e + 1.0f);
}
// no-clamp tanh (safe for finite inputs)
DEV float tanh_nc(float x){
  float e = __expf(2.0f*x);
  return 1.0f - 2.0f/(e + 1.0f);
}
DEV float sigm(float x){ return 1.0f / (1.0f + __expf(-x)); }
DEV float wredsum(float v){
  #pragma unroll
  for (int off=32; off; off>>=1) v += __shfl_xor(v, off, 64);
  return v;
}
DEV short f2b(float f){
  __hip_bfloat16 h = __float2bfloat16(f);
  return *reinterpret_cast<short*>(&h);
}
DEV float b2f(short s){
  unsigned int x = ((unsigned int)(unsigned short)s) << 16;
  return __uint_as_float(x);
}
DEV unsigned int cvt_pk_bf16(float lo, float hi){
  unsigned int r;
  asm("v_cvt_pk_bf16_f32 %0, %1, %2" : "=v"(r) : "v"(lo), "v"(hi));
  return r;
}
DEV unsigned int swz_xor1u(unsigned int v){
  return (unsigned int)__builtin_amdgcn_ds_swizzle((int)v, 0x041F);
}
DEV unsigned int permb(unsigned int hi_src, unsigned int lo_src, unsigned int sel){
  return __builtin_amdgcn_perm(hi_src, lo_src, sel);
}

// ---------- f32 -> bf16 bulk convert (n multiple of 4) ----------
__global__ void k_cvt_bf16(const float* __restrict__ src, short* __restrict__ dst, long n4){
  long i = (long)blockIdx.x*256 + threadIdx.x;
  if (i < n4){
    f32x4 v = *(const f32x4*)(src + i*4);
    s16x4 o;
    #pragma unroll
    for (int q=0;q<4;q++) o[q] = f2b(v[q]);
    *(s16x4*)(dst + i*4) = o;
  }
}

// ---------- sdec[b,u] = S_prev[b,:] @ W_dec ----------
__global__ void k_sdec(const float* __restrict__ S, const float* __restrict__ Wd,
                       float* __restrict__ sdec){
  int b = blockIdx.x, u = threadIdx.x;
  const float* s = S + b*DENC_;
  float acc = 0.f;
  #pragma unroll 4
  for (int d=0; d<DENC_; d++) acc += s[d]*Wd[d*U_+u];
  sdec[b*U_+u] = acc;
}

// ---------- bah = h_enc @ W_enc + sdec  (MFMA), bf16 out ----------
__global__ __launch_bounds__(256)
void k_bah_mfma(const float* __restrict__ h_enc, const short* __restrict__ Wenc_bf,
                const float* __restrict__ sdec, short* __restrict__ bah16){
  __shared__ short Wl[128*136];        // [col][k within 128-half], 34.8 KB
  int tid = threadIdx.x;
  int m0 = blockIdx.x * 64;
  int lane = tid & 63, wid = tid >> 6;
  int pl = lane & 15, g = lane >> 4;
  long arow = m0 + wid*16 + pl;
  const float* ap = h_enc + arow*DENC_;
  f32x4 acc[8];
  #pragma unroll
  for (int i=0;i<8;i++) acc[i] = (f32x4){0.f,0.f,0.f,0.f};

  for (int kh=0; kh<2; kh++){
    for (int i=tid; i<16384; i+=256){
      int k = i >> 7, c = i & 127;
      Wl[c*136 + k] = Wenc_bf[(kh*128 + k)*U_ + c];
    }
    __syncthreads();
    #pragma unroll
    for (int kk=0; kk<4; kk++){
      f32x4 a0 = *(const f32x4*)(ap + kh*128 + kk*32 + g*8);
      f32x4 a1 = *(const f32x4*)(ap + kh*128 + kk*32 + g*8 + 4);
      s16x8 a;
      #pragma unroll
      for (int q=0;q<4;q++){ a[q] = f2b(a0[q]); a[4+q] = f2b(a1[q]); }
      #pragma unroll
      for (int nt=0; nt<8; nt++){
        s16x8 b = *(const s16x8*)(Wl + (nt*16+pl)*136 + kk*32 + g*8);
        acc[nt] = __builtin_amdgcn_mfma_f32_16x16x32_bf16(a, b, acc[nt], 0,0,0);
      }
    }
    __syncthreads();
  }
  int b = m0 / T_;
  #pragma unroll
  for (int nt=0; nt<8; nt++){
    float sd = sdec[b*U_ + nt*16 + pl];
    #pragma unroll
    for (int q=0; q<4; q++){
      long r = m0 + wid*16 + g*4 + q;
      bah16[r*U_ + nt*16 + pl] = f2b(acc[nt][q] + sd);
    }
  }
}

// ---------- attention MLP via MFMA ----------
__global__ __launch_bounds__(256)
void k_att_mfma(const short* __restrict__ bah16, const float* __restrict__ W1,
                const float* __restrict__ W2, const float* __restrict__ W3f,
                float* __restrict__ e_out){
  __shared__ short W1l[64*136];   // [c][k], 17.4 KB
  __shared__ short W2l[32*72];    // [c][k], 4.6 KB
  __shared__ float hl[64][68];    // 17.4 KB
  __shared__ float w3s[32];
  int tid = threadIdx.x;
  int lane = tid & 63, wid = tid >> 6;
  int pl = lane & 15, g = lane >> 4;
  long m0 = (long)blockIdx.x * 64;

  for (int i=tid; i<8192; i+=256){ int k=i>>6, c=i&63; W1l[c*136+k] = f2b(W1[k*64+c]); }
  for (int i=tid; i<2048; i+=256){ int k=i>>5, c=i&31; W2l[c*72+k]  = f2b(W2[k*32+c]); }
  if (tid < 32) w3s[tid] = W3f[tid];
  __syncthreads();

  // layer 1: [64,128]@[128,64]
  const short* Ab = bah16 + (m0 + wid*16 + pl)*U_;
  f32x4 acc1[4];
  #pragma unroll
  for (int i=0;i<4;i++) acc1[i]=(f32x4){0.f,0.f,0.f,0.f};
  #pragma unroll
  for (int kk=0; kk<4; kk++){
    s16x8 a = *(const s16x8*)(Ab + kk*32 + g*8);
    #pragma unroll
    for (int nt=0; nt<4; nt++){
      s16x8 b = *(const s16x8*)(&W1l[(nt*16+pl)*136 + kk*32 + g*8]);
      acc1[nt] = __builtin_amdgcn_mfma_f32_16x16x32_bf16(a, b, acc1[nt], 0,0,0);
    }
  }
  #pragma unroll
  for (int nt=0; nt<4; nt++)
    #pragma unroll
    for (int q=0; q<4; q++)
      hl[wid*16 + g*4 + q][nt*16 + pl] = tanh_fast(acc1[nt][q]);
  __syncthreads();

  // layer 2: [64,64]@[64,32]
  f32x4 acc2[2];
  #pragma unroll
  for (int i=0;i<2;i++) acc2[i]=(f32x4){0.f,0.f,0.f,0.f};
  #pragma unroll
  for (int kk=0; kk<2; kk++){
    f32x4 h0 = *(const f32x4*)(&hl[wid*16+pl][kk*32 + g*8]);
    f32x4 h1 = *(const f32x4*)(&hl[wid*16+pl][kk*32 + g*8 + 4]);
    s16x8 a;
    #pragma unroll
    for (int q=0;q<4;q++){ a[q]=f2b(h0[q]); a[4+q]=f2b(h1[q]); }
    #pragma unroll
    for (int nt=0; nt<2; nt++){
      s16x8 b = *(const s16x8*)(&W2l[(nt*16+pl)*72 + kk*32 + g*8]);
      acc2[nt] = __builtin_amdgcn_mfma_f32_16x16x32_bf16(a, b, acc2[nt], 0,0,0);
    }
  }
  #pragma unroll
  for (int q=0; q<4; q++){
    float v = fmaxf(acc2[0][q],0.f)*w3s[pl] + fmaxf(acc2[1][q],0.f)*w3s[16+pl];
    #pragma unroll
    for (int off=1; off<16; off<<=1) v += __shfl_xor(v, off, 64);
    if (pl == 0) e_out[m0 + wid*16 + g*4 + q] = fmaxf(v, 0.f);
  }
}

// ---------- softmax over T per batch ----------
__global__ __launch_bounds__(256)
void k_softmax(const float* __restrict__ e, float* __restrict__ aw){
  int b = blockIdx.x, tid = threadIdx.x;
  __shared__ float red[4];
  const float* eb = e + (long)b*T_;
  float m = -1e30f;
  for (int t=tid; t<T_; t+=256) m = fmaxf(m, eb[t]);
  #pragma unroll
  for (int off=32; off; off>>=1) m = fmaxf(m, __shfl_xor(m, off, 64));
  if ((tid&63)==0) red[tid>>6] = m;
  __syncthreads();
  m = fmaxf(fmaxf(red[0],red[1]), fmaxf(red[2],red[3]));
  __syncthreads();
  float s = 0.f;
  for (int t=tid; t<T_; t+=256) s += __expf(eb[t]-m);
  s = wredsum(s);
  if ((tid&63)==0) red[tid>>6] = s;
  __syncthreads();
  s = red[0]+red[1]+red[2]+red[3];
  float inv = 1.0f/s;
  float* awb = aw + (long)b*T_;
  for (int t=tid; t<T_; t+=256) awb[t] = __expf(eb[t]-m)*inv;
}

// ---------- conv1 via MFMA, dy-packed K (k = dy*8+dx), no LDS/barriers ----------
// bah16 [n][48][128] bf16 -> c1 [n][45][125*8] bf16 (pixel 124 by k_c1edge).
// Block = (n, strip). One MFMA per 16-px tile per row (2 tiles). Weight cols
// 8-15 duplicate 0-7 so hi-lanes own tile a1 directly (no takeover shuffle).
#define C1LOAD(SL, LR) { \
    fa[SL] = *(const s16x8*)(xb + (long)((LR)+g)*128 + Tw + pl); \
    fb[SL] = *(const s16x8*)(xb + (long)((LR)+g)*128 + Tw + 16 + pl); }
#define C1PHASE(P) { \
    int ldr_ = base + (P) + 3; if (ldr_ > p1) ldr_ = p1; \
    C1LOAD(((P)+3)&3, ldr_); \
    f32x4 A0 = (f32x4){0.f,0.f,0.f,0.f}, A1 = A0; \
    A0 = __builtin_amdgcn_mfma_f32_16x16x32_bf16(fa[(P)&3], bw, A0, 0,0,0); \
    A1 = __builtin_amdgcn_mfma_f32_16x16x32_bf16(fb[(P)&3], bw, A1, 0,0,0); \
    epi(A0, A1, opg + (P)*1000, base + (P)); }

__global__ __launch_bounds__(256)
void k_conv1m(const short* __restrict__ bah16, const float* __restrict__ k1,
              const float* __restrict__ b1, short* __restrict__ c1){
  int s = blockIdx.x & 1;
  int n = blockIdx.x >> 1;
  int tid = threadIdx.x, lane = tid & 63, wid = tid >> 6;
  int pl = lane & 15, g = lane >> 4;
  int ch = pl & 7;
  bool hi = (pl >= 8);
  bool odd = (ch & 1);

  int ps0 = s ? 23 : 0;
  int p1  = s ? 45 : 23;    // conv rows [ps0,p1]; stores pooled ps0..p1-1

  // B frag: k=g*8+i -> dy=g, dx=i (valid g<3,i<3); col ch duplicated hi/lo
  s16x8 bw;
  #pragma unroll
  for (int i=0; i<8; i++)
    bw[i] = (g < 3 && i < 3) ? f2b(k1[(g*3 + i)*8 + ch]) : (short)0;
  float bo = b1[ch];

  int Tw = 31*wid;
  int qa = odd ? 2 : 0;
  int pixb = Tw + (hi ? 16 : 0) + 4*g + qa;
  int sbase = pixb*8 + (ch & ~1);            // shorts within row
  bool vd1 = !(hi && odd && g == 3);         // boundary pixel masked (edge kernel)
  int bpa = ((lane + 16) & 63) * 4;

  const short* xb = bah16 + (long)n*48*128;
  short* opg = c1 + (long)n*45*1000 + (long)(ps0 - 1)*1000;

  s16x8 fa[4], fb[4];
  C1LOAD(0, ps0);
  C1LOAD(1, ps0+1);
  C1LOAD(2, ps0+2);

  float vp[4] = {0.f,0.f,0.f,0.f};

  auto epi = [&](const f32x4& A0, const f32x4& A1, short* rowptr, int row){
    float a0q = hi ? A1[0] : A0[0];
    float a1q = hi ? A1[1] : A0[1];
    float a2q = hi ? A1[2] : A0[2];
    float a3q = hi ? A1[3] : A0[3];
    float nb = __int_as_float(__builtin_amdgcn_ds_bpermute(bpa, __float_as_int(a0q)));
    float nxt3 = (g == 3) ? A1[0] : nb;      // pl<8 g3: own a1[0]; hi g3: dead (masked)
    float w0 = fmaxf(a0q, a1q);
    float w1 = fmaxf(a1q, a2q);
    float w2 = fmaxf(a2q, a3q);
    float w3 = fmaxf(a3q, nxt3);
    if (row > ps0){
      float t0 = tanh_nc(fmaxf(vp[0], w0) + bo);
      float t1 = tanh_nc(fmaxf(vp[1], w1) + bo);
      float t2 = tanh_nc(fmaxf(vp[2], w2) + bo);
      float t3 = tanh_nc(fmaxf(vp[3], w3) + bo);
      unsigned int A  = cvt_pk_bf16(t0, t1);
      unsigned int Bp = cvt_pk_bf16(t2, t3);
      unsigned int An = swz_xor1u(A);
      unsigned int Bn = swz_xor1u(Bp);
      unsigned int ph = odd ? Bp : An;
      unsigned int pw = odd ? Bn : A;
      unsigned int d0 = permb(ph, pw, 0x05040100u);
      unsigned int d1 = permb(ph, pw, 0x07060302u);
      *(unsigned int*)(rowptr + sbase) = d0;
      if (vd1) *(unsigned int*)(rowptr + sbase + 8) = d1;
    }
    vp[0]=w0; vp[1]=w1; vp[2]=w2; vp[3]=w3;
  };

  int base = ps0;
  for (; base + 3 <= p1; base += 4){
    C1PHASE(0)
    C1PHASE(1)
    C1PHASE(2)
    C1PHASE(3)
    opg += 4*1000;
  }
  int rem = p1 - base + 1;
  if (rem > 0){ C1PHASE(0) }
  if (rem > 1){ C1PHASE(1) }
  if (rem > 2){ C1PHASE(2) }
}
#undef C1PHASE
#undef C1LOAD

// ---------- conv1 edge: pooled pixel 124 for all (n, r) ----------
__global__ void k_c1edge(const short* __restrict__ bah16, const float* __restrict__ k1,
                         const float* __restrict__ b1, short* __restrict__ c1){
  int idx = blockIdx.x*256 + threadIdx.x;   // n*45 + r
  if (idx >= NSM_*45) return;
  int n = idx / 45, r = idx % 45;
  const short* xb = bah16 + (long)n*48*128;
  float x[4][4];
  #pragma unroll
  for (int i=0;i<4;i++)
    #pragma unroll
    for (int j=0;j<4;j++) x[i][j] = b2f(xb[(long)(r+i)*128 + 124 + j]);
  short* ob = c1 + (long)n*45*1000 + (long)r*1000 + 124*8;
  #pragma unroll
  for (int c=0;c<8;c++){
    float best = -1e30f;
    #pragma unroll
    for (int pr=0; pr<2; pr++){
      #pragma unroll
      for (int px=0; px<2; px++){
        float v = 0.f;
        #pragma unroll
        for (int dy=0;dy<3;dy++)
          #pragma unroll
          for (int dx=0;dx<3;dx++)
            v += x[pr+dy][px+dx] * k1[(dy*3+dx)*8 + c];
        best = fmaxf(best, v);
      }
    }
    ob[c] = f2b(tanh_nc(best + b1[c]));
  }
}

// ---------- fused conv2 + convy, weight-packed MFMA ----------
#define LOADF(SL, OFF) { fa[SL] = *(const s16x8*)(gp + (OFF)); \
                         fb[SL] = *(const s16x8*)(gp + (OFF) + 128); }
#define CONVROW(SA,SB,SC, A0, A1) {                                          \
    A0 = (f32x4){0.f,0.f,0.f,0.f}; A1 = A0;                                  \
    A0 = __builtin_amdgcn_mfma_f32_16x16x32_bf16(fa[SA], bw[0], A0,0,0,0);   \
    A0 = __builtin_amdgcn_mfma_f32_16x16x32_bf16(fa[SB], bw[1], A0,0,0,0);   \
    A0 = __builtin_amdgcn_mfma_f32_16x16x32_bf16(fa[SC], bw[2], A0,0,0,0);   \
    A1 = __builtin_amdgcn_mfma_f32_16x16x32_bf16(fb[SA], bw[0], A1,0,0,0);   \
    A1 = __builtin_amdgcn_mfma_f32_16x16x32_bf16(fb[SB], bw[1], A1,0,0,0);   \
    A1 = __builtin_amdgcn_mfma_f32_16x16x32_bf16(fb[SC], bw[2], A1,0,0,0); }
#define PHASE(P) {                                                           \
    int ldr_ = base + (P) + 3; if (ldr_ > pmax_in) ldr_ = pmax_in;           \
    LOADF(((P)+3)&3, (long)(ldr_ - base)*1000);                              \
    f32x4 a0_, a1_;                                                          \
    CONVROW((P)&3, ((P)+1)&3, ((P)+2)&3, a0_, a1_);                          \
    epi(a0_, a1_, opg + (P)*976, base + (P));                                \
  }

__global__ __launch_bounds__(256)
void k_convf(const short* __restrict__ c1,
             const float* __restrict__ k2, const float* __restrict__ b2,
             const float* __restrict__ ky, const float* __restrict__ by,
             short* __restrict__ c2m, short* __restrict__ cy){
  int s  = blockIdx.x & 1;
  int nm = blockIdx.x >> 1;
  int n = nm / 12, m = nm % 12;
  int tid = threadIdx.x, lane = tid & 63, wid = tid >> 6;
  int pl = lane & 15, g = lane >> 4;
  bool isY = (pl >= 8);
  int ch = pl & 7;
  bool odd = (ch & 1);

  int rl_end = (m < 11) ? 45 : 42;
  int ps0 = s ? 23 : 0;
  int p1  = s ? rl_end : 23;
  int pmax_in = p1 + 2;

  const float* kern = isY ? ky : k2;
  s16x8 bw[3];
  #pragma unroll
  for (int dy=0; dy<3; dy++){
    #pragma unroll
    for (int i=0; i<8; i++){
      int k = g*8 + i;
      bw[dy][i] = (k < 24) ? f2b(kern[(dy*24 + k)*8 + ch]) : (short)0;
    }
  }
  float bo = isY ? by[ch] : b2[ch];

  int Tw = 31*wid;
  int qa = odd ? 2 : 0;
  int s0off = (Tw + g*4 + qa)*8 + (ch & ~1);   // shorts
  bool v1a = (Tw + 16 + g*4 + qa)     <= 121;
  bool v1b = ((Tw + 16 + g*4 + qa + 1) <= 121) && !(odd && g == 3);
  int bpa16 = ((lane+16)&63)*4;
  int bpaPL = pl*4;

  const short* gp = c1 + ((long)n*540 + 45*m + ps0)*1000 + (size_t)((Tw + pl + g)*8);
  short* opg = isY ? (cy  + ((long)n*537 + (long)45*m + ps0 - 1)*976)
                   : (c2m + ((long)(n*12+m)*42 + ps0 - 1)*976);

  s16x8 fa[4], fb[4];
  LOADF(0, 0);
  LOADF(1, 1000);
  LOADF(2, 2000);

  float vp[8];
  #pragma unroll
  for (int i=0;i<8;i++) vp[i]=0.f;

  auto epi = [&](const f32x4& a0, const f32x4& a1, short* rowptr, int row){
    float n0 = __int_as_float(__builtin_amdgcn_ds_bpermute(bpa16, __float_as_int(a0[0])));
    float n1 = __int_as_float(__builtin_amdgcn_ds_bpermute(bpa16, __float_as_int(a1[0])));
    float nbv = __int_as_float(__builtin_amdgcn_ds_bpermute(bpaPL, __float_as_int(a1[0])));
    float nxt0 = (g < 3) ? n0 : nbv;
    float w[8];
    w[0]=fmaxf(a0[0],a0[1]); w[1]=fmaxf(a0[1],a0[2]);
    w[2]=fmaxf(a0[2],a0[3]); w[3]=fmaxf(a0[3],nxt0);
    w[4]=fmaxf(a1[0],a1[1]); w[5]=fmaxf(a1[1],a1[2]);
    w[6]=fmaxf(a1[2],a1[3]); w[7]=fmaxf(a1[3],n1);
    bool en = (row > ps0) && (isY || row <= 42);
    if (en){
      float t0 = tanh_nc(fmaxf(vp[0], w[0]) + bo);
      float t1 = tanh_nc(fmaxf(vp[1], w[1]) + bo);
      float t2 = tanh_nc(fmaxf(vp[2], w[2]) + bo);
      float t3 = tanh_nc(fmaxf(vp[3], w[3]) + bo);
      float t4 = tanh_nc(fmaxf(vp[4], w[4]) + bo);
      float t5 = tanh_nc(fmaxf(vp[5], w[5]) + bo);
      float t6 = tanh_nc(fmaxf(vp[6], w[6]) + bo);
      float t7 = tanh_nc(fmaxf(vp[7], w[7]) + bo);
      unsigned int A  = cvt_pk_bf16(t0, t1);
      unsigned int Bp = cvt_pk_bf16(t2, t3);
      unsigned int An = swz_xor1u(A);
      unsigned int Bn = swz_xor1u(Bp);
      unsigned int ph = odd ? Bp : An;
      unsigned int pw = odd ? Bn : A;
      unsigned int d0 = permb(ph, pw, 0x05040100u);
      unsigned int d1 = permb(ph, pw, 0x07060302u);
      unsigned int C  = cvt_pk_bf16(t4, t5);
      unsigned int Dp = cvt_pk_bf16(t6, t7);
      unsigned int Cn = swz_xor1u(C);
      unsigned int Dn = swz_xor1u(Dp);
      unsigned int qh = odd ? Dp : Cn;
      unsigned int qw = odd ? Dn : C;
      unsigned int d2 = permb(qh, qw, 0x05040100u);
      unsigned int d3 = permb(qh, qw, 0x07060302u);
      *(unsigned int*)(rowptr + s0off)       = d0;
      *(unsigned int*)(rowptr + s0off + 8)   = d1;
      if (v1a) *(unsigned int*)(rowptr + s0off + 128) = d2;
      if (v1b) *(unsigned int*)(rowptr + s0off + 136) = d3;
    }
    #pragma unroll
    for (int i=0;i<8;i++) vp[i] = w[i];
  };

  int base = ps0;
  for (; base + 3 <= p1; base += 4){
    PHASE(0)
    PHASE(1)
    PHASE(2)
    PHASE(3)
    gp += 4000; opg += 4*976;
  }
  int rem = p1 - base + 1;
  if (rem > 0){ PHASE(0) }
  if (rem > 1){ PHASE(1) }
  if (rem > 2){ PHASE(2) }
}
#undef PHASE
#undef CONVROW
#undef LOADF

// ---------- C[i] = bias[i&63] ----------
__global__ void k_init64(float* __restrict__ C, const float* __restrict__ bias, int n){
  int i = blockIdx.x*256 + threadIdx.x;
  if (i < n) C[i] = bias[i & 63];
}

// ---------- MFMA split-K GEMM, K-step 64, double-buffered, high-occupancy ----------
__global__ __launch_bounds__(256)
void k_gemm64m(const __hip_bfloat16* __restrict__ A, const float* __restrict__ W,
               float* __restrict__ C, int Mrows, long Kdim, int mtiles, int spc){
  __shared__ short Ws_t[2][64*72];     // [buf][c][k(64)+8pad], 2×9.2 KB
  int mt = blockIdx.x % mtiles;
  int kc = blockIdx.x / mtiles;
  long nsteps = (Kdim + 63) >> 6;
  long s0 = (long)kc * spc;
  if (s0 >= nsteps) return;
  long s1 = min(nsteps, s0 + (long)spc);
  int m0 = mt * 64;
  int tid = threadIdx.x;
  int lane = tid & 63, wid = tid >> 6;
  int pl = lane & 15, g = lane >> 4;
  long arow = m0 + wid*16 + pl;
  if (arow >= Mrows) arow = 0;         // masked at write
  const short* Ab = (const short*)A + arow*Kdim;
  int wc = tid & 63, wk0 = (tid >> 6)*2;   // W staging: column wc, k pairs wk0+8j
  f32x4 acc[4];
  #pragma unroll
  for (int i=0;i<4;i++) acc[i]=(f32x4){0.f,0.f,0.f,0.f};

  float wr[16];
  auto loadW = [&](long s, float* w){
    long kb = s << 6;
    #pragma unroll
    for (int j=0;j<8;j++){
      long kg = kb + wk0 + j*8;
      w[2*j]   = (kg   < Kdim) ? W[kg*64 + wc]     : 0.f;
      w[2*j+1] = (kg+1 < Kdim) ? W[(kg+1)*64 + wc] : 0.f;
    }
  };
  auto writeW = [&](int buf, const float* w){
    #pragma unroll
    for (int j=0;j<8;j++){
      unsigned int p = cvt_pk_bf16(w[2*j], w[2*j+1]);
      *(unsigned int*)(&Ws_t[buf][wc*72 + wk0 + j*8]) = p;
    }
  };
  s16x8 aA[2], aN[2];
  auto loadA = [&](long s, s16x8* a){
    long kb = s << 6;
    #pragma unroll
    for (int kk=0;kk<2;kk++){
      long ko = kb + kk*32 + g*8;
      a[kk] = (ko < Kdim) ? *(const s16x8*)(Ab + ko) : (s16x8){0,0,0,0,0,0,0,0};
    }
  };

  loadW(s0, wr);
  loadA(s0, aA);
  writeW(0, wr);
  __syncthreads();
  int cur = 0;
  for (long s = s0; s < s1; ++s){
    bool more = (s+1 < s1);
    float wrn[16];
    if (more){ loadW(s+1, wrn); loadA(s+1, aN); }
    #pragma unroll
    for (int kk=0; kk<2; kk++){
      #pragma unroll
      for (int nt=0; nt<4; nt++){
        s16x8 b = *(const s16x8*)(&Ws_t[cur][(nt*16+pl)*72 + kk*32 + g*8]);
        acc[nt] = __builtin_amdgcn_mfma_f32_16x16x32_bf16(aA[kk], b, acc[nt], 0,0,0);
      }
    }
    if (more){
      __syncthreads();
      writeW(cur^1, wrn);
      __syncthreads();
      aA[0] = aN[0]; aA[1] = aN[1];
      cur ^= 1;
    }
  }
  #pragma unroll
  for (int nt=0; nt<4; nt++){
    #pragma unroll
    for (int q=0; q<4; q++){
      int r = m0 + wid*16 + g*4 + q;
      if (r < Mrows) atomicAdd(&C[(long)r*64 + nt*16 + pl], acc[nt][q]);
    }
  }
}

// ---------- month head ----------
__global__ void k_month_head(const float* __restrict__ em_pre, const float* __restrict__ Wm2,
                             const float* __restrict__ bm2, float* __restrict__ m_att){
  int g = blockIdx.x;          // b*10+y
  int tid = threadIdx.x;       // 64
  __shared__ float em[M_];
  float w2 = Wm2[tid];
  for (int m=0; m<M_; m++){
    float v = tanh_fast(em_pre[(g*M_+m)*64 + tid]) * w2;
    v = wredsum(v);
    if (tid==0) em[m] = fmaxf(v + bm2[0], 0.f);
  }
  __syncthreads();
  if (tid==0){
    float mx = -1e30f;
    for (int m=0;m<M_;m++) mx = fmaxf(mx, em[m]);
    float s=0.f; float ex[M_];
    for (int m=0;m<M_;m++){ ex[m]=__expf(em[m]-mx); s+=ex[m]; }
    float inv = 1.0f/s;
    for (int m=0;m<M_;m++) m_att[g*M_+m] = ex[m]*inv;
  }
}

// ---------- year head ----------
__global__ void k_year_head(const float* __restrict__ ey_pre, const float* __restrict__ Wy2,
                            const float* __restrict__ by2, float* __restrict__ y_att){
  int b = blockIdx.x;
  int tid = threadIdx.x;       // 64
  __shared__ float ey[Y_];
  float w2 = Wy2[tid];
  for (int y=0; y<Y_; y++){
    float v = tanh_fast(ey_pre[(b*Y_+y)*64 + tid]) * w2;
    v = wredsum(v);
    if (tid==0) ey[y] = fmaxf(v + by2[0], 0.f);
  }
  __syncthreads();
  if (tid==0){
    float mx = -1e30f;
    for (int y=0;y<Y_;y++) mx = fmaxf(mx, ey[y]);
    float s=0.f; float ex[Y_];
    for (int y=0;y<Y_;y++){ ex[y]=__expf(ey[y]-mx); s+=ex[y]; }
    float inv = 1.0f/s;
    for (int y=0;y<Y_;y++) y_att[b*Y_+y] = ex[y]*inv;
  }
}

// ---------- new_w = aw * m_att * y_att ----------
__global__ void k_new_w(const float* __restrict__ aw, const float* __restrict__ m_att,
                        const float* __restrict__ y_att, float* __restrict__ nw){
  int idx = blockIdx.x*256 + threadIdx.x;
  if (idx < B_*T_){
    int b = idx / T_, t = idx % T_;
    int y = t / (M_*WIN_), m = (t % (M_*WIN_)) / WIN_;
    nw[idx] = aw[idx] * m_att[(b*Y_+y)*M_+m] * y_att[b*Y_+y];
  }
}

__global__ void k_zero(float* __restrict__ p, int n){
  int i = blockIdx.x*256 + threadIdx.x; if (i<n) p[i]=0.f;
}

// ---------- ctx[b,d] = sum_t nw[b,t]*h_enc[b,t,d] (64 t-chunks) ----------
__global__ __launch_bounds__(256)
void k_ctx(const float* __restrict__ nw, const float* __restrict__ h_enc,
           float* __restrict__ ctx){
  int b = blockIdx.x >> 6, ch = blockIdx.x & 63;
  int d = threadIdx.x;
  float acc = 0.f;
  int t0 = ch*(T_/64), t1 = t0 + (T_/64);
  for (int t=t0; t<t1; t++)
    acc += nw[b*T_+t] * h_enc[((long)b*T_+t)*DENC_ + d];
  atomicAdd(&ctx[b*DENC_+d], acc);
}

// ---------- LSTM pre-activations ----------
__global__ void k_lstm_z(const float* __restrict__ ctx, const float* __restrict__ dec,
                         const float* __restrict__ S, const float* __restrict__ Wl,
                         const float* __restrict__ Ul, const float* __restrict__ bl,
                         float* __restrict__ z){
  int b = blockIdx.x >> 2;
  int j = (blockIdx.x & 3)*256 + threadIdx.x;
  float acc = bl[j];
  const float* cb = ctx + b*DENC_;
  const float* db = dec + b*FDEC_;
  const float* sb = S + b*RNN_;
  #pragma unroll 4
  for (int d=0; d<DENC_; d++) acc += cb[d]*Wl[d*1024 + j];
  #pragma unroll 4
  for (int d=0; d<FDEC_; d++) acc += db[d]*Wl[(DENC_+d)*1024 + j];
  #pragma unroll 4
  for (int d=0; d<RNN_; d++) acc += sb[d]*Ul[d*1024 + j];
  z[b*1024 + j] = acc;
}

__global__ void k_gates(const float* __restrict__ z, const float* __restrict__ Cprev,
                        float* __restrict__ h_out, float* __restrict__ c_out){
  int b = blockIdx.x, j = threadIdx.x;
  const float* zb = z + b*1024;
  float iv = sigm(zb[j]);
  float fv = sigm(zb[256+j]);
  float gv = tanh_fast(zb[512+j]);
  float ov = sigm(zb[768+j]);
  float c = fv*Cprev[b*RNN_+j] + iv*gv;
  float h = ov*tanh_fast(c);
  h_out[b*RNN_+j] = h;
  c_out[b*RNN_+j] = c;
}

__global__ void k_out(const float* __restrict__ h, const float* __restrict__ Wo,
                      const float* __restrict__ bo, float* __restrict__ out){
  int b = blockIdx.x, q = threadIdx.x; // 64
  float acc = bo[q];
  #pragma unroll 4
  for (int j=0; j<RNN_; j++) acc += h[b*RNN_+j]*Wo[j*64+q];
  out[b*64+q] = fmaxf(acc, 0.f);
}

extern "C" void kernel_launch(void* const* d_in, const int* in_sizes, int n_in,
                              void* d_out, int out_size, void* d_ws, size_t ws_size,
                              hipStream_t stream){
  const float* dec_input = (const float*)d_in[0];
  const float* S_prev = (const float*)d_in[1];
  const float* C_prev = (const float*)d_in[2];
  const float* h_enc  = (const float*)d_in[3];
  const float* W_enc  = (const float*)d_in[4];
  const float* W_dec  = (const float*)d_in[5];
  const float* W_att1 = (const float*)d_in[6];
  const float* W_att2 = (const float*)d_in[7];
  const float* W_att3 = (const float*)d_in[8];
  const float* conv1_k= (const float*)d_in[9];
  const float* conv1_b= (const float*)d_in[10];
  const float* conv2_k= (const float*)d_in[11];
  const float* conv2_b= (const float*)d_in[12];
  const float* convy_k= (const float*)d_in[13];
  const float* convy_b= (const float*)d_in[14];
  const float* Wm1    = (const float*)d_in[15];
  const float* bm1    = (const float*)d_in[16];
  const float* Wm2    = (const float*)d_in[17];
  const float* bm2    = (const float*)d_in[18];
  const float* Wy1    = (const float*)d_in[19];
  const float* by1    = (const float*)d_in[20];
  const float* Wy2    = (const float*)d_in[21];
  const float* by2    = (const float*)d_in[22];
  const float* W_lstm = (const float*)d_in[23];
  const float* U_lstm = (const float*)d_in[24];
  const float* b_lstm = (const float*)d_in[25];
  const float* W_out  = (const float*)d_in[26];
  const float* b_out  = (const float*)d_in[27];

  char* ws = (char*)d_ws;
  size_t off = 0;
  auto alloc = [&](size_t bytes)->char*{
    char* p = ws + off; off += (bytes + 255) & ~(size_t)255; return p;
  };
  short* bah16          = (short*)alloc((size_t)B_*T_*U_*2);                    // 23.6 MB
  short* c1             = (short*)alloc((size_t)NSM_*H1_*W1_*K_*2);             // 172.8 MB
  short* c2m            = (short*)alloc((size_t)NSM_*H2_*W2_*K_*2);             // 157.4 MB
  short* cy             = (short*)alloc((size_t)NSY_*HY_*WY_*K_*2);             // 167.7 MB
  float* e              = (float*)alloc((size_t)B_*T_*4);
  float* aw             = (float*)alloc((size_t)B_*T_*4);
  float* sdec           = (float*)alloc(B_*U_*4);
  float* em_pre         = (float*)alloc(NSM_*64*4);
  float* ey_pre         = (float*)alloc(NSY_*64*4);
  float* m_att          = (float*)alloc(NSM_*4);
  float* y_att          = (float*)alloc(NSY_*4);
  float* ctx            = (float*)alloc(B_*DENC_*4);
  float* zbuf           = (float*)alloc(B_*1024*4);
  short* Wenc_bf        = (short*)alloc(DENC_*U_*2);                            // 64 KB

  float* out   = (float*)d_out;              // [16,1,64]
  float* h_new = out + 1024;                 // [16,256]
  float* c_new = h_new + 4096;               // [16,256]
  float* nw    = c_new + 4096;               // [16,5760]

  k_cvt_bf16<<<(DENC_*U_/4 + 255)/256, 256, 0, stream>>>(W_enc, Wenc_bf, DENC_*U_/4);
  k_sdec<<<B_, U_, 0, stream>>>(S_prev, W_dec, sdec);
  k_bah_mfma<<<(B_*T_)/64, 256, 0, stream>>>(h_enc, Wenc_bf, sdec, bah16);
  k_att_mfma<<<(B_*T_)/64, 256, 0, stream>>>(bah16, W_att1, W_att2, W_att3, e);
  k_softmax<<<B_, 256, 0, stream>>>(e, aw);
  k_conv1m<<<NSM_*2, 256, 0, stream>>>(bah16, conv1_k, conv1_b, c1);
  k_c1edge<<<(NSM_*45 + 255)/256, 256, 0, stream>>>(bah16, conv1_k, conv1_b, c1);
  // fused conv2 + convy over c1 (year view [160][540][1000]), 2 row-strips
  k_convf<<<NSY_*12*2, 256, 0, stream>>>(c1, conv2_k, conv2_b, convy_k, convy_b, c2m, cy);
  k_init64<<<(NSM_*64+255)/256, 256, 0, stream>>>(em_pre, bm1, NSM_*64);
  // FLATM: K-step 64 -> nsteps=641, kchunks=81, spc=8 -> grid 2430
  k_gemm64m<<<81*30, 256, 0, stream>>>((const __hip_bfloat16*)c2m, Wm1, em_pre, NSM_, (long)FLATM_, 30, 8);
  k_month_head<<<NSY_, 64, 0, stream>>>(em_pre, Wm2, bm2, m_att);
  k_init64<<<(NSY_*64+255)/256, 256, 0, stream>>>(ey_pre, by1, NSY_*64);
  // FLATY: K-step 64 -> nsteps=8190, kchunks=512, spc=16 -> grid 1536
  k_gemm64m<<<512*3, 256, 0, stream>>>((const __hip_bfloat16*)cy, Wy1, ey_pre, NSY_, (long)FLATY_, 3, 16);
  k_year_head<<<B_, 64, 0, stream>>>(ey_pre, Wy2, by2, y_att);
  k_new_w<<<(B_*T_+255)/256, 256, 0, stream>>>(aw, m_att, y_att, nw);
  k_zero<<<(B_*DENC_+255)/256, 256, 0, stream>>>(ctx, B_*DENC_);
  k_ctx<<<B_*64, 256, 0, stream>>>(nw, h_enc, ctx);
  k_lstm_z<<<B_*4, 256, 0, stream>>>(ctx, dec_input, S_prev, W_lstm, U_lstm, b_lstm, zbuf);
  k_gates<<<B_, 256, 0, stream>>>(zbuf, C_prev, h_new, c_new);
  k_out<<<B_, 64, 0, stream>>>(h_new, W_out, b_out, out);
}

// Round 17
// 621.561 us; speedup vs baseline: 1.1263x; 1.1263x over previous
//
#include <hip/hip_runtime.h>
#include <hip/hip_bf16.h>

#define DEV static __device__ __forceinline__

// ---- static dims ----
#define B_    16
#define Y_    10
#define M_    12
#define WIN_  48
#define T_    5760     // Y*M*WIN
#define DENC_ 256
#define U_    128
#define A1_   64
#define A2_   32
#define K_    8
#define RNN_  256
#define FDEC_ 64
#define NOUT_ 64

#define H1_   45
#define W1_   125
#define H2_   42
#define W2_   122
#define FLATM_ 40992   // H2*W2*K
#define HY_   537
#define WY_   122
#define FLATY_ 524112  // HY*WY*K
#define NSM_  1920     // B*Y*M
#define NSY_  160      // B*Y

typedef __attribute__((ext_vector_type(8))) short s16x8;
typedef __attribute__((ext_vector_type(4))) short s16x4;
typedef __attribute__((ext_vector_type(4))) float f32x4;

DEV float rcpf(float x){ return __builtin_amdgcn_rcpf(x); }
DEV float tanh_fast(float x){
  x = fminf(fmaxf(x, -15.0f), 15.0f);
  float e = __expf(2.0f*x);
  return 1.0f - 2.0f*rcpf(e + 1.0f);
}
// no-clamp tanh (safe for finite inputs; rcp(inf)=0 -> 1)
DEV float tanh_nc(float x){
  float e = __expf(2.0f*x);
  return 1.0f - 2.0f*rcpf(e + 1.0f);
}
DEV float sigm(float x){ return rcpf(1.0f + __expf(-x)); }
DEV float wredsum(float v){
  #pragma unroll
  for (int off=32; off; off>>=1) v += __shfl_xor(v, off, 64);
  return v;
}
DEV short f2b(float f){
  __hip_bfloat16 h = __float2bfloat16(f);
  return *reinterpret_cast<short*>(&h);
}
DEV float b2f(short s){
  unsigned int x = ((unsigned int)(unsigned short)s) << 16;
  return __uint_as_float(x);
}
DEV unsigned int cvt_pk_bf16(float lo, float hi){
  unsigned int r;
  asm("v_cvt_pk_bf16_f32 %0, %1, %2" : "=v"(r) : "v"(lo), "v"(hi));
  return r;
}
DEV unsigned int swz_xor1u(unsigned int v){
  return (unsigned int)__builtin_amdgcn_ds_swizzle((int)v, 0x041F);
}
DEV unsigned int permb(unsigned int hi_src, unsigned int lo_src, unsigned int sel){
  return __builtin_amdgcn_perm(hi_src, lo_src, sel);
}

// ---------- f32 -> bf16 bulk convert (n multiple of 4) ----------
__global__ void k_cvt_bf16(const float* __restrict__ src, short* __restrict__ dst, long n4){
  long i = (long)blockIdx.x*256 + threadIdx.x;
  if (i < n4){
    f32x4 v = *(const f32x4*)(src + i*4);
    s16x4 o;
    #pragma unroll
    for (int q=0;q<4;q++) o[q] = f2b(v[q]);
    *(s16x4*)(dst + i*4) = o;
  }
}

// ---------- sdec[b,u] = S_prev[b,:] @ W_dec ----------
__global__ void k_sdec(const float* __restrict__ S, const float* __restrict__ Wd,
                       float* __restrict__ sdec){
  int b = blockIdx.x, u = threadIdx.x;
  const float* s = S + b*DENC_;
  float acc = 0.f;
  #pragma unroll 4
  for (int d=0; d<DENC_; d++) acc += s[d]*Wd[d*U_+u];
  sdec[b*U_+u] = acc;
}

// ---------- bah = h_enc @ W_enc + sdec  (MFMA), bf16 out ----------
__global__ __launch_bounds__(256)
void k_bah_mfma(const float* __restrict__ h_enc, const short* __restrict__ Wenc_bf,
                const float* __restrict__ sdec, short* __restrict__ bah16){
  __shared__ short Wl[128*136];        // [col][k within 128-half], 34.8 KB
  int tid = threadIdx.x;
  int m0 = blockIdx.x * 64;
  int lane = tid & 63, wid = tid >> 6;
  int pl = lane & 15, g = lane >> 4;
  long arow = m0 + wid*16 + pl;
  const float* ap = h_enc + arow*DENC_;
  f32x4 acc[8];
  #pragma unroll
  for (int i=0;i<8;i++) acc[i] = (f32x4){0.f,0.f,0.f,0.f};

  for (int kh=0; kh<2; kh++){
    for (int i=tid; i<16384; i+=256){
      int k = i >> 7, c = i & 127;
      Wl[c*136 + k] = Wenc_bf[(kh*128 + k)*U_ + c];
    }
    __syncthreads();
    #pragma unroll
    for (int kk=0; kk<4; kk++){
      f32x4 a0 = *(const f32x4*)(ap + kh*128 + kk*32 + g*8);
      f32x4 a1 = *(const f32x4*)(ap + kh*128 + kk*32 + g*8 + 4);
      s16x8 a;
      #pragma unroll
      for (int q=0;q<4;q++){ a[q] = f2b(a0[q]); a[4+q] = f2b(a1[q]); }
      #pragma unroll
      for (int nt=0; nt<8; nt++){
        s16x8 b = *(const s16x8*)(Wl + (nt*16+pl)*136 + kk*32 + g*8);
        acc[nt] = __builtin_amdgcn_mfma_f32_16x16x32_bf16(a, b, acc[nt], 0,0,0);
      }
    }
    __syncthreads();
  }
  int b = m0 / T_;
  #pragma unroll
  for (int nt=0; nt<8; nt++){
    float sd = sdec[b*U_ + nt*16 + pl];
    #pragma unroll
    for (int q=0; q<4; q++){
      long r = m0 + wid*16 + g*4 + q;
      bah16[r*U_ + nt*16 + pl] = f2b(acc[nt][q] + sd);
    }
  }
}

// ---------- attention MLP via MFMA ----------
__global__ __launch_bounds__(256)
void k_att_mfma(const short* __restrict__ bah16, const float* __restrict__ W1,
                const float* __restrict__ W2, const float* __restrict__ W3f,
                float* __restrict__ e_out){
  __shared__ short W1l[64*136];   // [c][k], 17.4 KB
  __shared__ short W2l[32*72];    // [c][k], 4.6 KB
  __shared__ float hl[64][68];    // 17.4 KB
  __shared__ float w3s[32];
  int tid = threadIdx.x;
  int lane = tid & 63, wid = tid >> 6;
  int pl = lane & 15, g = lane >> 4;
  long m0 = (long)blockIdx.x * 64;

  for (int i=tid; i<8192; i+=256){ int k=i>>6, c=i&63; W1l[c*136+k] = f2b(W1[k*64+c]); }
  for (int i=tid; i<2048; i+=256){ int k=i>>5, c=i&31; W2l[c*72+k]  = f2b(W2[k*32+c]); }
  if (tid < 32) w3s[tid] = W3f[tid];
  __syncthreads();

  // layer 1: [64,128]@[128,64]
  const short* Ab = bah16 + (m0 + wid*16 + pl)*U_;
  f32x4 acc1[4];
  #pragma unroll
  for (int i=0;i<4;i++) acc1[i]=(f32x4){0.f,0.f,0.f,0.f};
  #pragma unroll
  for (int kk=0; kk<4; kk++){
    s16x8 a = *(const s16x8*)(Ab + kk*32 + g*8);
    #pragma unroll
    for (int nt=0; nt<4; nt++){
      s16x8 b = *(const s16x8*)(&W1l[(nt*16+pl)*136 + kk*32 + g*8]);
      acc1[nt] = __builtin_amdgcn_mfma_f32_16x16x32_bf16(a, b, acc1[nt], 0,0,0);
    }
  }
  #pragma unroll
  for (int nt=0; nt<4; nt++)
    #pragma unroll
    for (int q=0; q<4; q++)
      hl[wid*16 + g*4 + q][nt*16 + pl] = tanh_fast(acc1[nt][q]);
  __syncthreads();

  // layer 2: [64,64]@[64,32]
  f32x4 acc2[2];
  #pragma unroll
  for (int i=0;i<2;i++) acc2[i]=(f32x4){0.f,0.f,0.f,0.f};
  #pragma unroll
  for (int kk=0; kk<2; kk++){
    f32x4 h0 = *(const f32x4*)(&hl[wid*16+pl][kk*32 + g*8]);
    f32x4 h1 = *(const f32x4*)(&hl[wid*16+pl][kk*32 + g*8 + 4]);
    s16x8 a;
    #pragma unroll
    for (int q=0;q<4;q++){ a[q]=f2b(h0[q]); a[4+q]=f2b(h1[q]); }
    #pragma unroll
    for (int nt=0; nt<2; nt++){
      s16x8 b = *(const s16x8*)(&W2l[(nt*16+pl)*72 + kk*32 + g*8]);
      acc2[nt] = __builtin_amdgcn_mfma_f32_16x16x32_bf16(a, b, acc2[nt], 0,0,0);
    }
  }
  #pragma unroll
  for (int q=0; q<4; q++){
    float v = fmaxf(acc2[0][q],0.f)*w3s[pl] + fmaxf(acc2[1][q],0.f)*w3s[16+pl];
    #pragma unroll
    for (int off=1; off<16; off<<=1) v += __shfl_xor(v, off, 64);
    if (pl == 0) e_out[m0 + wid*16 + g*4 + q] = fmaxf(v, 0.f);
  }
}

// ---------- softmax over T per batch ----------
__global__ __launch_bounds__(256)
void k_softmax(const float* __restrict__ e, float* __restrict__ aw){
  int b = blockIdx.x, tid = threadIdx.x;
  __shared__ float red[4];
  const float* eb = e + (long)b*T_;
  float m = -1e30f;
  for (int t=tid; t<T_; t+=256) m = fmaxf(m, eb[t]);
  #pragma unroll
  for (int off=32; off; off>>=1) m = fmaxf(m, __shfl_xor(m, off, 64));
  if ((tid&63)==0) red[tid>>6] = m;
  __syncthreads();
  m = fmaxf(fmaxf(red[0],red[1]), fmaxf(red[2],red[3]));
  __syncthreads();
  float s = 0.f;
  for (int t=tid; t<T_; t+=256) s += __expf(eb[t]-m);
  s = wredsum(s);
  if ((tid&63)==0) red[tid>>6] = s;
  __syncthreads();
  s = red[0]+red[1]+red[2]+red[3];
  float inv = 1.0f/s;
  float* awb = aw + (long)b*T_;
  for (int t=tid; t<T_; t+=256) awb[t] = __expf(eb[t]-m)*inv;
}

// ---------- conv1 strip + in-lane pool + packed stores ----------
__global__ __launch_bounds__(256)
void k_conv1s(const short* __restrict__ bah16, const float* __restrict__ k1,
              const float* __restrict__ b1, short* __restrict__ c1){
  int n = blockIdx.x >> 1, s = blockIdx.x & 1;
  int rp0 = s ? 23 : 0;            // pooled rows [rp0, rp1]
  int rp1 = s ? 44 : 22;
  int nin = rp1 + 4 - rp0;         // input rows staged (26 / 25)
  int tid = threadIdx.x;
  int lane = tid & 63, wid = tid >> 6;
  int c  = lane & 7;
  int wb = wid*8 + (lane >> 3);    // 0..31
  __shared__ float x[26][132];
  const short* xb = bah16 + (long)n*48*128 + rp0*128;
  for (int i=tid; i<nin*128; i+=256) x[i>>7][i&127] = b2f(xb[i]);
  for (int i=tid; i<26*4; i+=256)   x[i>>2][128+(i&3)] = 0.f;
  __syncthreads();

  float wk[9];
  #pragma unroll
  for (int p=0; p<9; p++) wk[p] = k1[p*8 + c];
  float bo = b1[c];
  bool odd = (c & 1);
  int qa = odd ? 2 : 0;
  bool va = (4*wb + qa)     <= 124;
  bool vb = (4*wb + qa + 1) <= 124;

  float rA[7], rB[7], rC[7];
  auto ldrow = [&](int rr, float* d){
    f32x4 a  = *(const f32x4*)(&x[rr][4*wb]);
    f32x4 b4 = *(const f32x4*)(&x[rr][4*wb+4]);
    d[0]=a[0]; d[1]=a[1]; d[2]=a[2]; d[3]=a[3]; d[4]=b4[0]; d[5]=b4[1]; d[6]=b4[2];
  };
  ldrow(0, rA); ldrow(1, rB);
  short* ob = c1 + (long)n*45*1000 + (long)rp0*1000;
  float vpc[4] = {0.f,0.f,0.f,0.f};
  int ncr = rp1 - rp0 + 2;         // conv rows this strip

  for (int rr=0; rr<ncr; ++rr){
    ldrow(rr+2, rC);
    float cv[5];
    #pragma unroll
    for (int q=0; q<5; q++){
      cv[q] = bo + rA[q]*wk[0] + rA[q+1]*wk[1] + rA[q+2]*wk[2]
                 + rB[q]*wk[3] + rB[q+1]*wk[4] + rB[q+2]*wk[5]
                 + rC[q]*wk[6] + rC[q+1]*wk[7] + rC[q+2]*wk[8];
    }
    float wcv[4];
    #pragma unroll
    for (int q=0; q<4; q++) wcv[q] = fmaxf(cv[q], cv[q+1]);
    if (rr > 0){
      float t0 = tanh_nc(fmaxf(vpc[0], wcv[0]));
      float t1 = tanh_nc(fmaxf(vpc[1], wcv[1]));
      float t2 = tanh_nc(fmaxf(vpc[2], wcv[2]));
      float t3 = tanh_nc(fmaxf(vpc[3], wcv[3]));
      unsigned int A  = cvt_pk_bf16(t0, t1);
      unsigned int Bp = cvt_pk_bf16(t2, t3);
      unsigned int An = swz_xor1u(A);
      unsigned int Bn = swz_xor1u(Bp);
      unsigned int ph = odd ? Bp : An;    // perm high-dword source
      unsigned int pw = odd ? Bn : A;     // perm low-dword source
      unsigned int w0 = permb(ph, pw, 0x05040100u);
      unsigned int w1 = permb(ph, pw, 0x07060302u);
      long rbase = (long)(rr-1)*1000 + (c & ~1);
      if (va) *(unsigned int*)(ob + rbase + (4*wb+qa)*8)   = w0;
      if (vb) *(unsigned int*)(ob + rbase + (4*wb+qa+1)*8) = w1;
    }
    #pragma unroll
    for (int q=0; q<4; q++) vpc[q] = wcv[q];
    #pragma unroll
    for (int q=0; q<7; q++){ rA[q]=rB[q]; rB[q]=rC[q]; }
  }
}

// ---------- fused conv2 + convy, weight-packed MFMA ----------
// B-cols 0-7 = conv2 weights, cols 8-15 = convy weights -> ONE set of 6 MFMAs
// per row computes both convs: lanes pl<8 hold conv2, lanes pl>=8 hold convy.
#define LOADF(SL, OFF) { fa[SL] = *(const s16x8*)(gp + (OFF)); \
                         fb[SL] = *(const s16x8*)(gp + (OFF) + 128); }
#define CONVROW(SA,SB,SC, A0, A1) {                                          \
    A0 = (f32x4){0.f,0.f,0.f,0.f}; A1 = A0;                                  \
    A0 = __builtin_amdgcn_mfma_f32_16x16x32_bf16(fa[SA], bw[0], A0,0,0,0);   \
    A0 = __builtin_amdgcn_mfma_f32_16x16x32_bf16(fa[SB], bw[1], A0,0,0,0);   \
    A0 = __builtin_amdgcn_mfma_f32_16x16x32_bf16(fa[SC], bw[2], A0,0,0,0);   \
    A1 = __builtin_amdgcn_mfma_f32_16x16x32_bf16(fb[SA], bw[0], A1,0,0,0);   \
    A1 = __builtin_amdgcn_mfma_f32_16x16x32_bf16(fb[SB], bw[1], A1,0,0,0);   \
    A1 = __builtin_amdgcn_mfma_f32_16x16x32_bf16(fb[SC], bw[2], A1,0,0,0); }
#define PHASE(P) {                                                           \
    int ldr_ = base + (P) + 3; if (ldr_ > pmax_in) ldr_ = pmax_in;           \
    LOADF(((P)+3)&3, (long)(ldr_ - base)*1000);                              \
    f32x4 a0_, a1_;                                                          \
    CONVROW((P)&3, ((P)+1)&3, ((P)+2)&3, a0_, a1_);                          \
    epi(a0_, a1_, opg + (P)*976, base + (P));                                \
  }

__global__ __launch_bounds__(256)
void k_convf(const short* __restrict__ c1,
             const float* __restrict__ k2, const float* __restrict__ b2,
             const float* __restrict__ ky, const float* __restrict__ by,
             short* __restrict__ c2m, short* __restrict__ cy){
  int s  = blockIdx.x & 1;
  int nm = blockIdx.x >> 1;
  int n = nm / 12, m = nm % 12;
  int tid = threadIdx.x, lane = tid & 63, wid = tid >> 6;
  int pl = lane & 15, g = lane >> 4;
  bool isY = (pl >= 8);
  int ch = pl & 7;
  bool odd = (ch & 1);

  int rl_end = (m < 11) ? 45 : 42;
  int ps0 = s ? 23 : 0;
  int p1  = s ? rl_end : 23;
  int pmax_in = p1 + 2;

  const float* kern = isY ? ky : k2;
  s16x8 bw[3];
  #pragma unroll
  for (int dy=0; dy<3; dy++){
    #pragma unroll
    for (int i=0; i<8; i++){
      int k = g*8 + i;
      bw[dy][i] = (k < 24) ? f2b(kern[(dy*24 + k)*8 + ch]) : (short)0;
    }
  }
  float bo = isY ? by[ch] : b2[ch];

  int Tw = 31*wid;
  int qa = odd ? 2 : 0;
  int s0off = (Tw + g*4 + qa)*8 + (ch & ~1);   // shorts
  bool v1a = (Tw + 16 + g*4 + qa)     <= 121;
  bool v1b = ((Tw + 16 + g*4 + qa + 1) <= 121) && !(odd && g == 3);
  int bpa16 = ((lane+16)&63)*4;
  int bpaPL = pl*4;

  const short* gp = c1 + ((long)n*540 + 45*m + ps0)*1000 + (size_t)((Tw + pl + g)*8);
  short* opg = isY ? (cy  + ((long)n*537 + (long)45*m + ps0 - 1)*976)
                   : (c2m + ((long)(n*12+m)*42 + ps0 - 1)*976);

  s16x8 fa[4], fb[4];
  LOADF(0, 0);
  LOADF(1, 1000);
  LOADF(2, 2000);

  float vp[8];
  #pragma unroll
  for (int i=0;i<8;i++) vp[i]=0.f;

  auto epi = [&](const f32x4& a0, const f32x4& a1, short* rowptr, int row){
    float n0 = __int_as_float(__builtin_amdgcn_ds_bpermute(bpa16, __float_as_int(a0[0])));
    float n1 = __int_as_float(__builtin_amdgcn_ds_bpermute(bpa16, __float_as_int(a1[0])));
    float nbv = __int_as_float(__builtin_amdgcn_ds_bpermute(bpaPL, __float_as_int(a1[0])));
    float nxt0 = (g < 3) ? n0 : nbv;
    float w[8];
    w[0]=fmaxf(a0[0],a0[1]); w[1]=fmaxf(a0[1],a0[2]);
    w[2]=fmaxf(a0[2],a0[3]); w[3]=fmaxf(a0[3],nxt0);
    w[4]=fmaxf(a1[0],a1[1]); w[5]=fmaxf(a1[1],a1[2]);
    w[6]=fmaxf(a1[2],a1[3]); w[7]=fmaxf(a1[3],n1);
    bool en = (row > ps0) && (isY || row <= 42);
    if (en){
      float t0 = tanh_nc(fmaxf(vp[0], w[0]) + bo);
      float t1 = tanh_nc(fmaxf(vp[1], w[1]) + bo);
      float t2 = tanh_nc(fmaxf(vp[2], w[2]) + bo);
      float t3 = tanh_nc(fmaxf(vp[3], w[3]) + bo);
      float t4 = tanh_nc(fmaxf(vp[4], w[4]) + bo);
      float t5 = tanh_nc(fmaxf(vp[5], w[5]) + bo);
      float t6 = tanh_nc(fmaxf(vp[6], w[6]) + bo);
      float t7 = tanh_nc(fmaxf(vp[7], w[7]) + bo);
      unsigned int A  = cvt_pk_bf16(t0, t1);
      unsigned int Bp = cvt_pk_bf16(t2, t3);
      unsigned int An = swz_xor1u(A);
      unsigned int Bn = swz_xor1u(Bp);
      unsigned int ph = odd ? Bp : An;
      unsigned int pw = odd ? Bn : A;
      unsigned int d0 = permb(ph, pw, 0x05040100u);
      unsigned int d1 = permb(ph, pw, 0x07060302u);
      unsigned int C  = cvt_pk_bf16(t4, t5);
      unsigned int Dp = cvt_pk_bf16(t6, t7);
      unsigned int Cn = swz_xor1u(C);
      unsigned int Dn = swz_xor1u(Dp);
      unsigned int qh = odd ? Dp : Cn;
      unsigned int qw = odd ? Dn : C;
      unsigned int d2 = permb(qh, qw, 0x05040100u);
      unsigned int d3 = permb(qh, qw, 0x07060302u);
      *(unsigned int*)(rowptr + s0off)       = d0;
      *(unsigned int*)(rowptr + s0off + 8)   = d1;
      if (v1a) *(unsigned int*)(rowptr + s0off + 128) = d2;
      if (v1b) *(unsigned int*)(rowptr + s0off + 136) = d3;
    }
    #pragma unroll
    for (int i=0;i<8;i++) vp[i] = w[i];
  };

  int base = ps0;
  for (; base + 3 <= p1; base += 4){
    PHASE(0)
    PHASE(1)
    PHASE(2)
    PHASE(3)
    gp += 4000; opg += 4*976;
  }
  int rem = p1 - base + 1;
  if (rem > 0){ PHASE(0) }
  if (rem > 1){ PHASE(1) }
  if (rem > 2){ PHASE(2) }
}
#undef PHASE
#undef CONVROW
#undef LOADF

// ---------- C[i] = bias[i&63] ----------
__global__ void k_init64(float* __restrict__ C, const float* __restrict__ bias, int n){
  int i = blockIdx.x*256 + threadIdx.x;
  if (i < n) C[i] = bias[i & 63];
}

// ---------- MFMA split-K GEMM, K-step 64, double-buffered, high-occupancy ----------
__global__ __launch_bounds__(256)
void k_gemm64m(const __hip_bfloat16* __restrict__ A, const float* __restrict__ W,
               float* __restrict__ C, int Mrows, long Kdim, int mtiles, int spc){
  __shared__ short Ws_t[2][64*72];     // [buf][c][k(64)+8pad], 2×9.2 KB
  int mt = blockIdx.x % mtiles;
  int kc = blockIdx.x / mtiles;
  long nsteps = (Kdim + 63) >> 6;
  long s0 = (long)kc * spc;
  if (s0 >= nsteps) return;
  long s1 = min(nsteps, s0 + (long)spc);
  int m0 = mt * 64;
  int tid = threadIdx.x;
  int lane = tid & 63, wid = tid >> 6;
  int pl = lane & 15, g = lane >> 4;
  long arow = m0 + wid*16 + pl;
  if (arow >= Mrows) arow = 0;         // masked at write
  const short* Ab = (const short*)A + arow*Kdim;
  int wc = tid & 63, wk0 = (tid >> 6)*2;   // W staging: column wc, k pairs wk0+8j
  f32x4 acc[4];
  #pragma unroll
  for (int i=0;i<4;i++) acc[i]=(f32x4){0.f,0.f,0.f,0.f};

  float wr[16];
  auto loadW = [&](long s, float* w){
    long kb = s << 6;
    #pragma unroll
    for (int j=0;j<8;j++){
      long kg = kb + wk0 + j*8;
      w[2*j]   = (kg   < Kdim) ? W[kg*64 + wc]     : 0.f;
      w[2*j+1] = (kg+1 < Kdim) ? W[(kg+1)*64 + wc] : 0.f;
    }
  };
  auto writeW = [&](int buf, const float* w){
    #pragma unroll
    for (int j=0;j<8;j++){
      unsigned int p = cvt_pk_bf16(w[2*j], w[2*j+1]);
      *(unsigned int*)(&Ws_t[buf][wc*72 + wk0 + j*8]) = p;
    }
  };
  s16x8 aA[2], aN[2];
  auto loadA = [&](long s, s16x8* a){
    long kb = s << 6;
    #pragma unroll
    for (int kk=0;kk<2;kk++){
      long ko = kb + kk*32 + g*8;
      a[kk] = (ko < Kdim) ? *(const s16x8*)(Ab + ko) : (s16x8){0,0,0,0,0,0,0,0};
    }
  };

  loadW(s0, wr);
  loadA(s0, aA);
  writeW(0, wr);
  __syncthreads();
  int cur = 0;
  for (long s = s0; s < s1; ++s){
    bool more = (s+1 < s1);
    float wrn[16];
    if (more){ loadW(s+1, wrn); loadA(s+1, aN); }
    #pragma unroll
    for (int kk=0; kk<2; kk++){
      #pragma unroll
      for (int nt=0; nt<4; nt++){
        s16x8 b = *(const s16x8*)(&Ws_t[cur][(nt*16+pl)*72 + kk*32 + g*8]);
        acc[nt] = __builtin_amdgcn_mfma_f32_16x16x32_bf16(aA[kk], b, acc[nt], 0,0,0);
      }
    }
    if (more){
      __syncthreads();
      writeW(cur^1, wrn);
      __syncthreads();
      aA[0] = aN[0]; aA[1] = aN[1];
      cur ^= 1;
    }
  }
  #pragma unroll
  for (int nt=0; nt<4; nt++){
    #pragma unroll
    for (int q=0; q<4; q++){
      int r = m0 + wid*16 + g*4 + q;
      if (r < Mrows) atomicAdd(&C[(long)r*64 + nt*16 + pl], acc[nt][q]);
    }
  }
}

// ---------- month head ----------
__global__ void k_month_head(const float* __restrict__ em_pre, const float* __restrict__ Wm2,
                             const float* __restrict__ bm2, float* __restrict__ m_att){
  int g = blockIdx.x;          // b*10+y
  int tid = threadIdx.x;       // 64
  __shared__ float em[M_];
  float w2 = Wm2[tid];
  for (int m=0; m<M_; m++){
    float v = tanh_fast(em_pre[(g*M_+m)*64 + tid]) * w2;
    v = wredsum(v);
    if (tid==0) em[m] = fmaxf(v + bm2[0], 0.f);
  }
  __syncthreads();
  if (tid==0){
    float mx = -1e30f;
    for (int m=0;m<M_;m++) mx = fmaxf(mx, em[m]);
    float s=0.f; float ex[M_];
    for (int m=0;m<M_;m++){ ex[m]=__expf(em[m]-mx); s+=ex[m]; }
    float inv = 1.0f/s;
    for (int m=0;m<M_;m++) m_att[g*M_+m] = ex[m]*inv;
  }
}

// ---------- year head ----------
__global__ void k_year_head(const float* __restrict__ ey_pre, const float* __restrict__ Wy2,
                            const float* __restrict__ by2, float* __restrict__ y_att){
  int b = blockIdx.x;
  int tid = threadIdx.x;       // 64
  __shared__ float ey[Y_];
  float w2 = Wy2[tid];
  for (int y=0; y<Y_; y++){
    float v = tanh_fast(ey_pre[(b*Y_+y)*64 + tid]) * w2;
    v = wredsum(v);
    if (tid==0) ey[y] = fmaxf(v + by2[0], 0.f);
  }
  __syncthreads();
  if (tid==0){
    float mx = -1e30f;
    for (int y=0;y<Y_;y++) mx = fmaxf(mx, ey[y]);
    float s=0.f; float ex[Y_];
    for (int y=0;y<Y_;y++){ ex[y]=__expf(ey[y]-mx); s+=ex[y]; }
    float inv = 1.0f/s;
    for (int y=0;y<Y_;y++) y_att[b*Y_+y] = ex[y]*inv;
  }
}

// ---------- new_w = aw * m_att * y_att ----------
__global__ void k_new_w(const float* __restrict__ aw, const float* __restrict__ m_att,
                        const float* __restrict__ y_att, float* __restrict__ nw){
  int idx = blockIdx.x*256 + threadIdx.x;
  if (idx < B_*T_){
    int b = idx / T_, t = idx % T_;
    int y = t / (M_*WIN_), m = (t % (M_*WIN_)) / WIN_;
    nw[idx] = aw[idx] * m_att[(b*Y_+y)*M_+m] * y_att[b*Y_+y];
  }
}

__global__ void k_zero(float* __restrict__ p, int n){
  int i = blockIdx.x*256 + threadIdx.x; if (i<n) p[i]=0.f;
}

// ---------- ctx[b,d] = sum_t nw[b,t]*h_enc[b,t,d] (64 t-chunks) ----------
__global__ __launch_bounds__(256)
void k_ctx(const float* __restrict__ nw, const float* __restrict__ h_enc,
           float* __restrict__ ctx){
  int b = blockIdx.x >> 6, ch = blockIdx.x & 63;
  int d = threadIdx.x;
  float acc = 0.f;
  int t0 = ch*(T_/64), t1 = t0 + (T_/64);
  for (int t=t0; t<t1; t++)
    acc += nw[b*T_+t] * h_enc[((long)b*T_+t)*DENC_ + d];
  atomicAdd(&ctx[b*DENC_+d], acc);
}

// ---------- LSTM pre-activations ----------
__global__ void k_lstm_z(const float* __restrict__ ctx, const float* __restrict__ dec,
                         const float* __restrict__ S, const float* __restrict__ Wl,
                         const float* __restrict__ Ul, const float* __restrict__ bl,
                         float* __restrict__ z){
  int b = blockIdx.x >> 2;
  int j = (blockIdx.x & 3)*256 + threadIdx.x;
  float acc = bl[j];
  const float* cb = ctx + b*DENC_;
  const float* db = dec + b*FDEC_;
  const float* sb = S + b*RNN_;
  #pragma unroll 4
  for (int d=0; d<DENC_; d++) acc += cb[d]*Wl[d*1024 + j];
  #pragma unroll 4
  for (int d=0; d<FDEC_; d++) acc += db[d]*Wl[(DENC_+d)*1024 + j];
  #pragma unroll 4
  for (int d=0; d<RNN_; d++) acc += sb[d]*Ul[d*1024 + j];
  z[b*1024 + j] = acc;
}

__global__ void k_gates(const float* __restrict__ z, const float* __restrict__ Cprev,
                        float* __restrict__ h_out, float* __restrict__ c_out){
  int b = blockIdx.x, j = threadIdx.x;
  const float* zb = z + b*1024;
  float iv = sigm(zb[j]);
  float fv = sigm(zb[256+j]);
  float gv = tanh_fast(zb[512+j]);
  float ov = sigm(zb[768+j]);
  float c = fv*Cprev[b*RNN_+j] + iv*gv;
  float h = ov*tanh_fast(c);
  h_out[b*RNN_+j] = h;
  c_out[b*RNN_+j] = c;
}

__global__ void k_out(const float* __restrict__ h, const float* __restrict__ Wo,
                      const float* __restrict__ bo, float* __restrict__ out){
  int b = blockIdx.x, q = threadIdx.x; // 64
  float acc = bo[q];
  #pragma unroll 4
  for (int j=0; j<RNN_; j++) acc += h[b*RNN_+j]*Wo[j*64+q];
  out[b*64+q] = fmaxf(acc, 0.f);
}

extern "C" void kernel_launch(void* const* d_in, const int* in_sizes, int n_in,
                              void* d_out, int out_size, void* d_ws, size_t ws_size,
                              hipStream_t stream){
  const float* dec_input = (const float*)d_in[0];
  const float* S_prev = (const float*)d_in[1];
  const float* C_prev = (const float*)d_in[2];
  const float* h_enc  = (const float*)d_in[3];
  const float* W_enc  = (const float*)d_in[4];
  const float* W_dec  = (const float*)d_in[5];
  const float* W_att1 = (const float*)d_in[6];
  const float* W_att2 = (const float*)d_in[7];
  const float* W_att3 = (const float*)d_in[8];
  const float* conv1_k= (const float*)d_in[9];
  const float* conv1_b= (const float*)d_in[10];
  const float* conv2_k= (const float*)d_in[11];
  const float* conv2_b= (const float*)d_in[12];
  const float* convy_k= (const float*)d_in[13];
  const float* convy_b= (const float*)d_in[14];
  const float* Wm1    = (const float*)d_in[15];
  const float* bm1    = (const float*)d_in[16];
  const float* Wm2    = (const float*)d_in[17];
  const float* bm2    = (const float*)d_in[18];
  const float* Wy1    = (const float*)d_in[19];
  const float* by1    = (const float*)d_in[20];
  const float* Wy2    = (const float*)d_in[21];
  const float* by2    = (const float*)d_in[22];
  const float* W_lstm = (const float*)d_in[23];
  const float* U_lstm = (const float*)d_in[24];
  const float* b_lstm = (const float*)d_in[25];
  const float* W_out  = (const float*)d_in[26];
  const float* b_out  = (const float*)d_in[27];

  char* ws = (char*)d_ws;
  size_t off = 0;
  auto alloc = [&](size_t bytes)->char*{
    char* p = ws + off; off += (bytes + 255) & ~(size_t)255; return p;
  };
  short* bah16          = (short*)alloc((size_t)B_*T_*U_*2);                    // 23.6 MB
  short* c1             = (short*)alloc((size_t)NSM_*H1_*W1_*K_*2);             // 172.8 MB
  short* c2m            = (short*)alloc((size_t)NSM_*H2_*W2_*K_*2);             // 157.4 MB
  short* cy             = (short*)alloc((size_t)NSY_*HY_*WY_*K_*2);             // 167.7 MB
  float* e              = (float*)alloc((size_t)B_*T_*4);
  float* aw             = (float*)alloc((size_t)B_*T_*4);
  float* sdec           = (float*)alloc(B_*U_*4);
  float* em_pre         = (float*)alloc(NSM_*64*4);
  float* ey_pre         = (float*)alloc(NSY_*64*4);
  float* m_att          = (float*)alloc(NSM_*4);
  float* y_att          = (float*)alloc(NSY_*4);
  float* ctx            = (float*)alloc(B_*DENC_*4);
  float* zbuf           = (float*)alloc(B_*1024*4);
  short* Wenc_bf        = (short*)alloc(DENC_*U_*2);                            // 64 KB

  float* out   = (float*)d_out;              // [16,1,64]
  float* h_new = out + 1024;                 // [16,256]
  float* c_new = h_new + 4096;               // [16,256]
  float* nw    = c_new + 4096;               // [16,5760]

  k_cvt_bf16<<<(DENC_*U_/4 + 255)/256, 256, 0, stream>>>(W_enc, Wenc_bf, DENC_*U_/4);
  k_sdec<<<B_, U_, 0, stream>>>(S_prev, W_dec, sdec);
  k_bah_mfma<<<(B_*T_)/64, 256, 0, stream>>>(h_enc, Wenc_bf, sdec, bah16);
  k_att_mfma<<<(B_*T_)/64, 256, 0, stream>>>(bah16, W_att1, W_att2, W_att3, e);
  k_softmax<<<B_, 256, 0, stream>>>(e, aw);
  k_conv1s<<<NSM_*2, 256, 0, stream>>>(bah16, conv1_k, conv1_b, c1);
  // fused conv2 + convy over c1 (year view [160][540][1000]), 2 row-strips
  k_convf<<<NSY_*12*2, 256, 0, stream>>>(c1, conv2_k, conv2_b, convy_k, convy_b, c2m, cy);
  k_init64<<<(NSM_*64+255)/256, 256, 0, stream>>>(em_pre, bm1, NSM_*64);
  // FLATM: K-step 64 -> nsteps=641, kchunks=81, spc=8 -> grid 2430
  k_gemm64m<<<81*30, 256, 0, stream>>>((const __hip_bfloat16*)c2m, Wm1, em_pre, NSM_, (long)FLATM_, 30, 8);
  k_month_head<<<NSY_, 64, 0, stream>>>(em_pre, Wm2, bm2, m_att);
  k_init64<<<(NSY_*64+255)/256, 256, 0, stream>>>(ey_pre, by1, NSY_*64);
  // FLATY: K-step 64 -> nsteps=8190, kchunks=512, spc=16 -> grid 1536
  k_gemm64m<<<512*3, 256, 0, stream>>>((const __hip_bfloat16*)cy, Wy1, ey_pre, NSY_, (long)FLATY_, 3, 16);
  k_year_head<<<B_, 64, 0, stream>>>(ey_pre, Wy2, by2, y_att);
  k_new_w<<<(B_*T_+255)/256, 256, 0, stream>>>(aw, m_att, y_att, nw);
  k_zero<<<(B_*DENC_+255)/256, 256, 0, stream>>>(ctx, B_*DENC_);
  k_ctx<<<B_*64, 256, 0, stream>>>(nw, h_enc, ctx);
  k_lstm_z<<<B_*4, 256, 0, stream>>>(ctx, dec_input, S_prev, W_lstm, U_lstm, b_lstm, zbuf);
  k_gates<<<B_, 256, 0, stream>>>(zbuf, C_prev, h_new, c_new);
  k_out<<<B_, 64, 0, stream>>>(h_new, W_out, b_out, out);
}

// Round 18
// 606.976 us; speedup vs baseline: 1.1534x; 1.0240x over previous
//
#include <hip/hip_runtime.h>
#include <hip/hip_bf16.h>

#define DEV static __device__ __forceinline__

// ---- static dims ----
#define B_    16
#define Y_    10
#define M_    12
#define WIN_  48
#define T_    5760     // Y*M*WIN
#define DENC_ 256
#define U_    128
#define A1_   64
#define A2_   32
#define K_    8
#define RNN_  256
#define FDEC_ 64
#define NOUT_ 64

#define H1_   45
#define W1_   125
#define H2_   42
#define W2_   122
#define FLATM_ 40992   // H2*W2*K
#define HY_   537
#define WY_   122
#define FLATY_ 524112  // HY*WY*K
#define NSM_  1920     // B*Y*M
#define NSY_  160      // B*Y

typedef __attribute__((ext_vector_type(8))) short s16x8;
typedef __attribute__((ext_vector_type(4))) short s16x4;
typedef __attribute__((ext_vector_type(4))) float f32x4;

DEV float rcpf(float x){ return __builtin_amdgcn_rcpf(x); }
DEV float tanh_fast(float x){
  x = fminf(fmaxf(x, -15.0f), 15.0f);
  float e = __expf(2.0f*x);
  return 1.0f - 2.0f*rcpf(e + 1.0f);
}
// no-clamp tanh (safe for finite inputs; rcp(inf)=0 -> 1)
DEV float tanh_nc(float x){
  float e = __expf(2.0f*x);
  return 1.0f - 2.0f*rcpf(e + 1.0f);
}
DEV float sigm(float x){ return rcpf(1.0f + __expf(-x)); }
DEV float wredsum(float v){
  #pragma unroll
  for (int off=32; off; off>>=1) v += __shfl_xor(v, off, 64);
  return v;
}
DEV short f2b(float f){
  __hip_bfloat16 h = __float2bfloat16(f);
  return *reinterpret_cast<short*>(&h);
}
DEV float b2f(short s){
  unsigned int x = ((unsigned int)(unsigned short)s) << 16;
  return __uint_as_float(x);
}
DEV unsigned int cvt_pk_bf16(float lo, float hi){
  unsigned int r;
  asm("v_cvt_pk_bf16_f32 %0, %1, %2" : "=v"(r) : "v"(lo), "v"(hi));
  return r;
}
DEV unsigned int swz_xor1u(unsigned int v){
  return (unsigned int)__builtin_amdgcn_ds_swizzle((int)v, 0x041F);
}
DEV unsigned int permb(unsigned int hi_src, unsigned int lo_src, unsigned int sel){
  return __builtin_amdgcn_perm(hi_src, lo_src, sel);
}

// ---------- fused setup: Wenc cvt + sdec + em/ey init + ctx zero ----------
__global__ __launch_bounds__(256)
void k_setup(const float* __restrict__ W_enc, short* __restrict__ Wenc_bf,
             const float* __restrict__ S, const float* __restrict__ Wd,
             float* __restrict__ sdec,
             const float* __restrict__ bm1, float* __restrict__ em_pre,
             const float* __restrict__ by1, float* __restrict__ ey_pre,
             float* __restrict__ ctx){
  int blk = blockIdx.x, tid = threadIdx.x;
  if (blk < 32){                       // W_enc f32 -> bf16 (32768 elems)
    int i = blk*256 + tid;             // 8192 quads
    f32x4 v = *(const f32x4*)(W_enc + (long)i*4);
    s16x4 o;
    #pragma unroll
    for (int q=0;q<4;q++) o[q] = f2b(v[q]);
    *(s16x4*)(Wenc_bf + (long)i*4) = o;
  } else if (blk < 48){                // sdec[b,u]
    int b = blk - 32;
    if (tid < U_){
      const float* s = S + b*DENC_;
      float acc = 0.f;
      #pragma unroll 4
      for (int d=0; d<DENC_; d++) acc += s[d]*Wd[d*U_+tid];
      sdec[b*U_+tid] = acc;
    }
  } else if (blk < 528){               // em_pre init (122880)
    int i = (blk-48)*256 + tid;
    em_pre[i] = bm1[i & 63];
  } else if (blk < 568){               // ey_pre init (10240)
    int i = (blk-528)*256 + tid;
    ey_pre[i] = by1[i & 63];
  } else {                             // ctx zero (4096)
    int i = (blk-568)*256 + tid;
    ctx[i] = 0.f;
  }
}

// ---------- fused bah + attention MLP ----------
// Phase A: bah = h_enc @ W_enc + sdec (MFMA, Wl staged in LDS).
// Phase B (LDS overlay): bahl (bf16 transpose of bah) + W1l + W2l + hlb;
// vectorized bah16 global write from bahl; att L1/L2 from LDS; e_out.
__global__ __launch_bounds__(256)
void k_bah_att(const float* __restrict__ h_enc, const short* __restrict__ Wenc_bf,
               const float* __restrict__ sdec,
               const float* __restrict__ W1, const float* __restrict__ W2,
               const float* __restrict__ W3f,
               short* __restrict__ bah16, float* __restrict__ e_out){
  __shared__ char smem[48768];
  short* Wl   = (short*)smem;             // [128*136], phase A (34816 B)
  short* bahl = (short*)smem;             // [64*136]  (17408 B)
  short* W1l  = (short*)(smem + 17408);   // [64*136]  (17408 B)
  short* W2l  = (short*)(smem + 34816);   // [32*72]   (4608 B)
  short* hlb  = (short*)(smem + 39424);   // [64*72]   (9216 B)
  float* w3s  = (float*)(smem + 48640);   // [32]
  int tid = threadIdx.x;
  int m0 = blockIdx.x * 64;
  int lane = tid & 63, wid = tid >> 6;
  int pl = lane & 15, g = lane >> 4;
  long arow = m0 + wid*16 + pl;
  const float* ap = h_enc + arow*DENC_;
  f32x4 acc[8];
  #pragma unroll
  for (int i=0;i<8;i++) acc[i] = (f32x4){0.f,0.f,0.f,0.f};

  for (int kh=0; kh<2; kh++){
    for (int i=tid; i<16384; i+=256){
      int k = i >> 7, c = i & 127;
      Wl[c*136 + k] = Wenc_bf[(kh*128 + k)*U_ + c];
    }
    __syncthreads();
    #pragma unroll
    for (int kk=0; kk<4; kk++){
      f32x4 a0 = *(const f32x4*)(ap + kh*128 + kk*32 + g*8);
      f32x4 a1 = *(const f32x4*)(ap + kh*128 + kk*32 + g*8 + 4);
      s16x8 a;
      #pragma unroll
      for (int q=0;q<4;q++){ a[q] = f2b(a0[q]); a[4+q] = f2b(a1[q]); }
      #pragma unroll
      for (int nt=0; nt<8; nt++){
        s16x8 b = *(const s16x8*)(Wl + (nt*16+pl)*136 + kk*32 + g*8);
        acc[nt] = __builtin_amdgcn_mfma_f32_16x16x32_bf16(a, b, acc[nt], 0,0,0);
      }
    }
    __syncthreads();
  }
  int b = m0 / T_;
  // phase B: write bahl (overlays Wl lower half) + stage W1l/W2l/w3s
  #pragma unroll
  for (int nt=0; nt<8; nt++){
    float sd = sdec[b*U_ + nt*16 + pl];
    #pragma unroll
    for (int q=0; q<4; q++)
      bahl[(wid*16 + g*4 + q)*136 + nt*16 + pl] = f2b(acc[nt][q] + sd);
  }
  for (int i=tid; i<8192; i+=256){ int k=i>>6, c=i&63; W1l[c*136+k] = f2b(W1[k*64+c]); }
  for (int i=tid; i<2048; i+=256){ int k=i>>5, c=i&31; W2l[c*72+k]  = f2b(W2[k*32+c]); }
  if (tid < 32) w3s[tid] = W3f[tid];
  __syncthreads();

  // vectorized coalesced bah16 global write from bahl
  for (int i=tid; i<1024; i+=256){       // 1024 chunks of 8 shorts
    int r = i >> 4, cc = (i & 15)*8;
    s16x8 v = *(const s16x8*)&bahl[r*136 + cc];
    *(s16x8*)&bah16[(long)(m0 + r)*U_ + cc] = v;
  }

  // att layer 1: [64,128]@[128,64]
  f32x4 acc1[4];
  #pragma unroll
  for (int i=0;i<4;i++) acc1[i]=(f32x4){0.f,0.f,0.f,0.f};
  #pragma unroll
  for (int kk=0; kk<4; kk++){
    s16x8 a = *(const s16x8*)&bahl[(wid*16+pl)*136 + kk*32 + g*8];
    #pragma unroll
    for (int nt=0; nt<4; nt++){
      s16x8 bb = *(const s16x8*)&W1l[(nt*16+pl)*136 + kk*32 + g*8];
      acc1[nt] = __builtin_amdgcn_mfma_f32_16x16x32_bf16(a, bb, acc1[nt], 0,0,0);
    }
  }
  #pragma unroll
  for (int nt=0; nt<4; nt++)
    #pragma unroll
    for (int q=0; q<4; q++)
      hlb[(wid*16 + g*4 + q)*72 + nt*16 + pl] = f2b(tanh_fast(acc1[nt][q]));
  __syncthreads();

  // att layer 2: [64,64]@[64,32]
  f32x4 acc2[2];
  #pragma unroll
  for (int i=0;i<2;i++) acc2[i]=(f32x4){0.f,0.f,0.f,0.f};
  #pragma unroll
  for (int kk=0; kk<2; kk++){
    s16x8 a = *(const s16x8*)&hlb[(wid*16+pl)*72 + kk*32 + g*8];
    #pragma unroll
    for (int nt=0; nt<2; nt++){
      s16x8 bb = *(const s16x8*)&W2l[(nt*16+pl)*72 + kk*32 + g*8];
      acc2[nt] = __builtin_amdgcn_mfma_f32_16x16x32_bf16(a, bb, acc2[nt], 0,0,0);
    }
  }
  #pragma unroll
  for (int q=0; q<4; q++){
    float v = fmaxf(acc2[0][q],0.f)*w3s[pl] + fmaxf(acc2[1][q],0.f)*w3s[16+pl];
    #pragma unroll
    for (int off=1; off<16; off<<=1) v += __shfl_xor(v, off, 64);
    if (pl == 0) e_out[(long)m0 + wid*16 + g*4 + q] = fmaxf(v, 0.f);
  }
}

// ---------- softmax over T per batch ----------
__global__ __launch_bounds__(256)
void k_softmax(const float* __restrict__ e, float* __restrict__ aw){
  int b = blockIdx.x, tid = threadIdx.x;
  __shared__ float red[4];
  const float* eb = e + (long)b*T_;
  float m = -1e30f;
  for (int t=tid; t<T_; t+=256) m = fmaxf(m, eb[t]);
  #pragma unroll
  for (int off=32; off; off>>=1) m = fmaxf(m, __shfl_xor(m, off, 64));
  if ((tid&63)==0) red[tid>>6] = m;
  __syncthreads();
  m = fmaxf(fmaxf(red[0],red[1]), fmaxf(red[2],red[3]));
  __syncthreads();
  float s = 0.f;
  for (int t=tid; t<T_; t+=256) s += __expf(eb[t]-m);
  s = wredsum(s);
  if ((tid&63)==0) red[tid>>6] = s;
  __syncthreads();
  s = red[0]+red[1]+red[2]+red[3];
  float inv = 1.0f/s;
  float* awb = aw + (long)b*T_;
  for (int t=tid; t<T_; t+=256) awb[t] = __expf(eb[t]-m)*inv;
}

// ---------- conv1 strip + in-lane pool + packed stores ----------
__global__ __launch_bounds__(256)
void k_conv1s(const short* __restrict__ bah16, const float* __restrict__ k1,
              const float* __restrict__ b1, short* __restrict__ c1){
  int n = blockIdx.x >> 1, s = blockIdx.x & 1;
  int rp0 = s ? 23 : 0;            // pooled rows [rp0, rp1]
  int rp1 = s ? 44 : 22;
  int nin = rp1 + 4 - rp0;         // input rows staged (26 / 25)
  int tid = threadIdx.x;
  int lane = tid & 63, wid = tid >> 6;
  int c  = lane & 7;
  int wb = wid*8 + (lane >> 3);    // 0..31
  __shared__ float x[26][132];
  const short* xb = bah16 + (long)n*48*128 + rp0*128;
  for (int i=tid; i<nin*128; i+=256) x[i>>7][i&127] = b2f(xb[i]);
  for (int i=tid; i<26*4; i+=256)   x[i>>2][128+(i&3)] = 0.f;
  __syncthreads();

  float wk[9];
  #pragma unroll
  for (int p=0; p<9; p++) wk[p] = k1[p*8 + c];
  float bo = b1[c];
  bool odd = (c & 1);
  int qa = odd ? 2 : 0;
  bool va = (4*wb + qa)     <= 124;
  bool vb = (4*wb + qa + 1) <= 124;

  float rA[7], rB[7], rC[7];
  auto ldrow = [&](int rr, float* d){
    f32x4 a  = *(const f32x4*)(&x[rr][4*wb]);
    f32x4 b4 = *(const f32x4*)(&x[rr][4*wb+4]);
    d[0]=a[0]; d[1]=a[1]; d[2]=a[2]; d[3]=a[3]; d[4]=b4[0]; d[5]=b4[1]; d[6]=b4[2];
  };
  ldrow(0, rA); ldrow(1, rB);
  short* ob = c1 + (long)n*45*1000 + (long)rp0*1000;
  float vpc[4] = {0.f,0.f,0.f,0.f};
  int ncr = rp1 - rp0 + 2;         // conv rows this strip

  for (int rr=0; rr<ncr; ++rr){
    ldrow(rr+2, rC);
    float cv[5];
    #pragma unroll
    for (int q=0; q<5; q++){
      cv[q] = bo + rA[q]*wk[0] + rA[q+1]*wk[1] + rA[q+2]*wk[2]
                 + rB[q]*wk[3] + rB[q+1]*wk[4] + rB[q+2]*wk[5]
                 + rC[q]*wk[6] + rC[q+1]*wk[7] + rC[q+2]*wk[8];
    }
    float wcv[4];
    #pragma unroll
    for (int q=0; q<4; q++) wcv[q] = fmaxf(cv[q], cv[q+1]);
    if (rr > 0){
      float t0 = tanh_nc(fmaxf(vpc[0], wcv[0]));
      float t1 = tanh_nc(fmaxf(vpc[1], wcv[1]));
      float t2 = tanh_nc(fmaxf(vpc[2], wcv[2]));
      float t3 = tanh_nc(fmaxf(vpc[3], wcv[3]));
      unsigned int A  = cvt_pk_bf16(t0, t1);
      unsigned int Bp = cvt_pk_bf16(t2, t3);
      unsigned int An = swz_xor1u(A);
      unsigned int Bn = swz_xor1u(Bp);
      unsigned int ph = odd ? Bp : An;    // perm high-dword source
      unsigned int pw = odd ? Bn : A;     // perm low-dword source
      unsigned int w0 = permb(ph, pw, 0x05040100u);
      unsigned int w1 = permb(ph, pw, 0x07060302u);
      long rbase = (long)(rr-1)*1000 + (c & ~1);
      if (va) *(unsigned int*)(ob + rbase + (4*wb+qa)*8)   = w0;
      if (vb) *(unsigned int*)(ob + rbase + (4*wb+qa+1)*8) = w1;
    }
    #pragma unroll
    for (int q=0; q<4; q++) vpc[q] = wcv[q];
    #pragma unroll
    for (int q=0; q<7; q++){ rA[q]=rB[q]; rB[q]=rC[q]; }
  }
}

// ---------- fused conv2 + convy, weight-packed MFMA ----------
// B-cols 0-7 = conv2 weights, cols 8-15 = convy weights -> ONE set of 6 MFMAs
// per row computes both convs: lanes pl<8 hold conv2, lanes pl>=8 hold convy.
#define LOADF(SL, OFF) { fa[SL] = *(const s16x8*)(gp + (OFF)); \
                         fb[SL] = *(const s16x8*)(gp + (OFF) + 128); }
#define CONVROW(SA,SB,SC, A0, A1) {                                          \
    A0 = (f32x4){0.f,0.f,0.f,0.f}; A1 = A0;                                  \
    A0 = __builtin_amdgcn_mfma_f32_16x16x32_bf16(fa[SA], bw[0], A0,0,0,0);   \
    A0 = __builtin_amdgcn_mfma_f32_16x16x32_bf16(fa[SB], bw[1], A0,0,0,0);   \
    A0 = __builtin_amdgcn_mfma_f32_16x16x32_bf16(fa[SC], bw[2], A0,0,0,0);   \
    A1 = __builtin_amdgcn_mfma_f32_16x16x32_bf16(fb[SA], bw[0], A1,0,0,0);   \
    A1 = __builtin_amdgcn_mfma_f32_16x16x32_bf16(fb[SB], bw[1], A1,0,0,0);   \
    A1 = __builtin_amdgcn_mfma_f32_16x16x32_bf16(fb[SC], bw[2], A1,0,0,0); }
#define PHASE(P) {                                                           \
    int ldr_ = base + (P) + 3; if (ldr_ > pmax_in) ldr_ = pmax_in;           \
    LOADF(((P)+3)&3, (long)(ldr_ - base)*1000);                              \
    f32x4 a0_, a1_;                                                          \
    CONVROW((P)&3, ((P)+1)&3, ((P)+2)&3, a0_, a1_);                          \
    epi(a0_, a1_, opg + (P)*976, base + (P));                                \
  }

__global__ __launch_bounds__(256)
void k_convf(const short* __restrict__ c1,
             const float* __restrict__ k2, const float* __restrict__ b2,
             const float* __restrict__ ky, const float* __restrict__ by,
             short* __restrict__ c2m, short* __restrict__ cy){
  int s  = blockIdx.x & 1;
  int nm = blockIdx.x >> 1;
  int n = nm / 12, m = nm % 12;
  int tid = threadIdx.x, lane = tid & 63, wid = tid >> 6;
  int pl = lane & 15, g = lane >> 4;
  bool isY = (pl >= 8);
  int ch = pl & 7;
  bool odd = (ch & 1);

  int rl_end = (m < 11) ? 45 : 42;
  int ps0 = s ? 23 : 0;
  int p1  = s ? rl_end : 23;
  int pmax_in = p1 + 2;

  const float* kern = isY ? ky : k2;
  s16x8 bw[3];
  #pragma unroll
  for (int dy=0; dy<3; dy++){
    #pragma unroll
    for (int i=0; i<8; i++){
      int k = g*8 + i;
      bw[dy][i] = (k < 24) ? f2b(kern[(dy*24 + k)*8 + ch]) : (short)0;
    }
  }
  float bo = isY ? by[ch] : b2[ch];

  int Tw = 31*wid;
  int qa = odd ? 2 : 0;
  int s0off = (Tw + g*4 + qa)*8 + (ch & ~1);   // shorts
  bool v1a = (Tw + 16 + g*4 + qa)     <= 121;
  bool v1b = ((Tw + 16 + g*4 + qa + 1) <= 121) && !(odd && g == 3);
  int bpa16 = ((lane+16)&63)*4;
  int bpaPL = pl*4;

  const short* gp = c1 + ((long)n*540 + 45*m + ps0)*1000 + (size_t)((Tw + pl + g)*8);
  short* opg = isY ? (cy  + ((long)n*537 + (long)45*m + ps0 - 1)*976)
                   : (c2m + ((long)(n*12+m)*42 + ps0 - 1)*976);

  s16x8 fa[4], fb[4];
  LOADF(0, 0);
  LOADF(1, 1000);
  LOADF(2, 2000);

  float vp[8];
  #pragma unroll
  for (int i=0;i<8;i++) vp[i]=0.f;

  auto epi = [&](const f32x4& a0, const f32x4& a1, short* rowptr, int row){
    float n0 = __int_as_float(__builtin_amdgcn_ds_bpermute(bpa16, __float_as_int(a0[0])));
    float n1 = __int_as_float(__builtin_amdgcn_ds_bpermute(bpa16, __float_as_int(a1[0])));
    float nbv = __int_as_float(__builtin_amdgcn_ds_bpermute(bpaPL, __float_as_int(a1[0])));
    float nxt0 = (g < 3) ? n0 : nbv;
    float w[8];
    w[0]=fmaxf(a0[0],a0[1]); w[1]=fmaxf(a0[1],a0[2]);
    w[2]=fmaxf(a0[2],a0[3]); w[3]=fmaxf(a0[3],nxt0);
    w[4]=fmaxf(a1[0],a1[1]); w[5]=fmaxf(a1[1],a1[2]);
    w[6]=fmaxf(a1[2],a1[3]); w[7]=fmaxf(a1[3],n1);
    bool en = (row > ps0) && (isY || row <= 42);
    if (en){
      float t0 = tanh_nc(fmaxf(vp[0], w[0]) + bo);
      float t1 = tanh_nc(fmaxf(vp[1], w[1]) + bo);
      float t2 = tanh_nc(fmaxf(vp[2], w[2]) + bo);
      float t3 = tanh_nc(fmaxf(vp[3], w[3]) + bo);
      float t4 = tanh_nc(fmaxf(vp[4], w[4]) + bo);
      float t5 = tanh_nc(fmaxf(vp[5], w[5]) + bo);
      float t6 = tanh_nc(fmaxf(vp[6], w[6]) + bo);
      float t7 = tanh_nc(fmaxf(vp[7], w[7]) + bo);
      unsigned int A  = cvt_pk_bf16(t0, t1);
      unsigned int Bp = cvt_pk_bf16(t2, t3);
      unsigned int An = swz_xor1u(A);
      unsigned int Bn = swz_xor1u(Bp);
      unsigned int ph = odd ? Bp : An;
      unsigned int pw = odd ? Bn : A;
      unsigned int d0 = permb(ph, pw, 0x05040100u);
      unsigned int d1 = permb(ph, pw, 0x07060302u);
      unsigned int C  = cvt_pk_bf16(t4, t5);
      unsigned int Dp = cvt_pk_bf16(t6, t7);
      unsigned int Cn = swz_xor1u(C);
      unsigned int Dn = swz_xor1u(Dp);
      unsigned int qh = odd ? Dp : Cn;
      unsigned int qw = odd ? Dn : C;
      unsigned int d2 = permb(qh, qw, 0x05040100u);
      unsigned int d3 = permb(qh, qw, 0x07060302u);
      *(unsigned int*)(rowptr + s0off)       = d0;
      *(unsigned int*)(rowptr + s0off + 8)   = d1;
      if (v1a) *(unsigned int*)(rowptr + s0off + 128) = d2;
      if (v1b) *(unsigned int*)(rowptr + s0off + 136) = d3;
    }
    #pragma unroll
    for (int i=0;i<8;i++) vp[i] = w[i];
  };

  int base = ps0;
  for (; base + 3 <= p1; base += 4){
    PHASE(0)
    PHASE(1)
    PHASE(2)
    PHASE(3)
    gp += 4000; opg += 4*976;
  }
  int rem = p1 - base + 1;
  if (rem > 0){ PHASE(0) }
  if (rem > 1){ PHASE(1) }
  if (rem > 2){ PHASE(2) }
}
#undef PHASE
#undef CONVROW
#undef LOADF

// ---------- MFMA split-K GEMM, K-step 64, double-buffered, high-occupancy ----------
__global__ __launch_bounds__(256)
void k_gemm64m(const __hip_bfloat16* __restrict__ A, const float* __restrict__ W,
               float* __restrict__ C, int Mrows, long Kdim, int mtiles, int spc){
  __shared__ short Ws_t[2][64*72];     // [buf][c][k(64)+8pad], 2×9.2 KB
  int mt = blockIdx.x % mtiles;
  int kc = blockIdx.x / mtiles;
  long nsteps = (Kdim + 63) >> 6;
  long s0 = (long)kc * spc;
  if (s0 >= nsteps) return;
  long s1 = min(nsteps, s0 + (long)spc);
  int m0 = mt * 64;
  int tid = threadIdx.x;
  int lane = tid & 63, wid = tid >> 6;
  int pl = lane & 15, g = lane >> 4;
  long arow = m0 + wid*16 + pl;
  if (arow >= Mrows) arow = 0;         // masked at write
  const short* Ab = (const short*)A + arow*Kdim;
  int wc = tid & 63, wk0 = (tid >> 6)*2;   // W staging: column wc, k pairs wk0+8j
  f32x4 acc[4];
  #pragma unroll
  for (int i=0;i<4;i++) acc[i]=(f32x4){0.f,0.f,0.f,0.f};

  float wr[16];
  auto loadW = [&](long s, float* w){
    long kb = s << 6;
    #pragma unroll
    for (int j=0;j<8;j++){
      long kg = kb + wk0 + j*8;
      w[2*j]   = (kg   < Kdim) ? W[kg*64 + wc]     : 0.f;
      w[2*j+1] = (kg+1 < Kdim) ? W[(kg+1)*64 + wc] : 0.f;
    }
  };
  auto writeW = [&](int buf, const float* w){
    #pragma unroll
    for (int j=0;j<8;j++){
      unsigned int p = cvt_pk_bf16(w[2*j], w[2*j+1]);
      *(unsigned int*)(&Ws_t[buf][wc*72 + wk0 + j*8]) = p;
    }
  };
  s16x8 aA[2], aN[2];
  auto loadA = [&](long s, s16x8* a){
    long kb = s << 6;
    #pragma unroll
    for (int kk=0;kk<2;kk++){
      long ko = kb + kk*32 + g*8;
      a[kk] = (ko < Kdim) ? *(const s16x8*)(Ab + ko) : (s16x8){0,0,0,0,0,0,0,0};
    }
  };

  loadW(s0, wr);
  loadA(s0, aA);
  writeW(0, wr);
  __syncthreads();
  int cur = 0;
  for (long s = s0; s < s1; ++s){
    bool more = (s+1 < s1);
    float wrn[16];
    if (more){ loadW(s+1, wrn); loadA(s+1, aN); }
    #pragma unroll
    for (int kk=0; kk<2; kk++){
      #pragma unroll
      for (int nt=0; nt<4; nt++){
        s16x8 b = *(const s16x8*)(&Ws_t[cur][(nt*16+pl)*72 + kk*32 + g*8]);
        acc[nt] = __builtin_amdgcn_mfma_f32_16x16x32_bf16(aA[kk], b, acc[nt], 0,0,0);
      }
    }
    if (more){
      __syncthreads();
      writeW(cur^1, wrn);
      __syncthreads();
      aA[0] = aN[0]; aA[1] = aN[1];
      cur ^= 1;
    }
  }
  #pragma unroll
  for (int nt=0; nt<4; nt++){
    #pragma unroll
    for (int q=0; q<4; q++){
      int r = m0 + wid*16 + g*4 + q;
      if (r < Mrows) atomicAdd(&C[(long)r*64 + nt*16 + pl], acc[nt][q]);
    }
  }
}

// ---------- month head ----------
__global__ void k_month_head(const float* __restrict__ em_pre, const float* __restrict__ Wm2,
                             const float* __restrict__ bm2, float* __restrict__ m_att){
  int g = blockIdx.x;          // b*10+y
  int tid = threadIdx.x;       // 64
  __shared__ float em[M_];
  float w2 = Wm2[tid];
  for (int m=0; m<M_; m++){
    float v = tanh_fast(em_pre[(g*M_+m)*64 + tid]) * w2;
    v = wredsum(v);
    if (tid==0) em[m] = fmaxf(v + bm2[0], 0.f);
  }
  __syncthreads();
  if (tid==0){
    float mx = -1e30f;
    for (int m=0;m<M_;m++) mx = fmaxf(mx, em[m]);
    float s=0.f; float ex[M_];
    for (int m=0;m<M_;m++){ ex[m]=__expf(em[m]-mx); s+=ex[m]; }
    float inv = 1.0f/s;
    for (int m=0;m<M_;m++) m_att[g*M_+m] = ex[m]*inv;
  }
}

// ---------- year head ----------
__global__ void k_year_head(const float* __restrict__ ey_pre, const float* __restrict__ Wy2,
                            const float* __restrict__ by2, float* __restrict__ y_att){
  int b = blockIdx.x;
  int tid = threadIdx.x;       // 64
  __shared__ float ey[Y_];
  float w2 = Wy2[tid];
  for (int y=0; y<Y_; y++){
    float v = tanh_fast(ey_pre[(b*Y_+y)*64 + tid]) * w2;
    v = wredsum(v);
    if (tid==0) ey[y] = fmaxf(v + by2[0], 0.f);
  }
  __syncthreads();
  if (tid==0){
    float mx = -1e30f;
    for (int y=0;y<Y_;y++) mx = fmaxf(mx, ey[y]);
    float s=0.f; float ex[Y_];
    for (int y=0;y<Y_;y++){ ex[y]=__expf(ey[y]-mx); s+=ex[y]; }
    float inv = 1.0f/s;
    for (int y=0;y<Y_;y++) y_att[b*Y_+y] = ex[y]*inv;
  }
}

// ---------- new_w = aw * m_att * y_att ----------
__global__ void k_new_w(const float* __restrict__ aw, const float* __restrict__ m_att,
                        const float* __restrict__ y_att, float* __restrict__ nw){
  int idx = blockIdx.x*256 + threadIdx.x;
  if (idx < B_*T_){
    int b = idx / T_, t = idx % T_;
    int y = t / (M_*WIN_), m = (t % (M_*WIN_)) / WIN_;
    nw[idx] = aw[idx] * m_att[(b*Y_+y)*M_+m] * y_att[b*Y_+y];
  }
}

// ---------- ctx[b,d] = sum_t nw[b,t]*h_enc[b,t,d] (64 t-chunks) ----------
__global__ __launch_bounds__(256)
void k_ctx(const float* __restrict__ nw, const float* __restrict__ h_enc,
           float* __restrict__ ctx){
  int b = blockIdx.x >> 6, ch = blockIdx.x & 63;
  int d = threadIdx.x;
  float acc = 0.f;
  int t0 = ch*(T_/64), t1 = t0 + (T_/64);
  for (int t=t0; t<t1; t++)
    acc += nw[b*T_+t] * h_enc[((long)b*T_+t)*DENC_ + d];
  atomicAdd(&ctx[b*DENC_+d], acc);
}

// ---------- LSTM pre-activations ----------
__global__ void k_lstm_z(const float* __restrict__ ctx, const float* __restrict__ dec,
                         const float* __restrict__ S, const float* __restrict__ Wl,
                         const float* __restrict__ Ul, const float* __restrict__ bl,
                         float* __restrict__ z){
  int b = blockIdx.x >> 2;
  int j = (blockIdx.x & 3)*256 + threadIdx.x;
  float acc = bl[j];
  const float* cb = ctx + b*DENC_;
  const float* db = dec + b*FDEC_;
  const float* sb = S + b*RNN_;
  #pragma unroll 4
  for (int d=0; d<DENC_; d++) acc += cb[d]*Wl[d*1024 + j];
  #pragma unroll 4
  for (int d=0; d<FDEC_; d++) acc += db[d]*Wl[(DENC_+d)*1024 + j];
  #pragma unroll 4
  for (int d=0; d<RNN_; d++) acc += sb[d]*Ul[d*1024 + j];
  z[b*1024 + j] = acc;
}

__global__ void k_gates(const float* __restrict__ z, const float* __restrict__ Cprev,
                        float* __restrict__ h_out, float* __restrict__ c_out){
  int b = blockIdx.x, j = threadIdx.x;
  const float* zb = z + b*1024;
  float iv = sigm(zb[j]);
  float fv = sigm(zb[256+j]);
  float gv = tanh_fast(zb[512+j]);
  float ov = sigm(zb[768+j]);
  float c = fv*Cprev[b*RNN_+j] + iv*gv;
  float h = ov*tanh_fast(c);
  h_out[b*RNN_+j] = h;
  c_out[b*RNN_+j] = c;
}

__global__ void k_out(const float* __restrict__ h, const float* __restrict__ Wo,
                      const float* __restrict__ bo, float* __restrict__ out){
  int b = blockIdx.x, q = threadIdx.x; // 64
  float acc = bo[q];
  #pragma unroll 4
  for (int j=0; j<RNN_; j++) acc += h[b*RNN_+j]*Wo[j*64+q];
  out[b*64+q] = fmaxf(acc, 0.f);
}

extern "C" void kernel_launch(void* const* d_in, const int* in_sizes, int n_in,
                              void* d_out, int out_size, void* d_ws, size_t ws_size,
                              hipStream_t stream){
  const float* dec_input = (const float*)d_in[0];
  const float* S_prev = (const float*)d_in[1];
  const float* C_prev = (const float*)d_in[2];
  const float* h_enc  = (const float*)d_in[3];
  const float* W_enc  = (const float*)d_in[4];
  const float* W_dec  = (const float*)d_in[5];
  const float* W_att1 = (const float*)d_in[6];
  const float* W_att2 = (const float*)d_in[7];
  const float* W_att3 = (const float*)d_in[8];
  const float* conv1_k= (const float*)d_in[9];
  const float* conv1_b= (const float*)d_in[10];
  const float* conv2_k= (const float*)d_in[11];
  const float* conv2_b= (const float*)d_in[12];
  const float* convy_k= (const float*)d_in[13];
  const float* convy_b= (const float*)d_in[14];
  const float* Wm1    = (const float*)d_in[15];
  const float* bm1    = (const float*)d_in[16];
  const float* Wm2    = (const float*)d_in[17];
  const float* bm2    = (const float*)d_in[18];
  const float* Wy1    = (const float*)d_in[19];
  const float* by1    = (const float*)d_in[20];
  const float* Wy2    = (const float*)d_in[21];
  const float* by2    = (const float*)d_in[22];
  const float* W_lstm = (const float*)d_in[23];
  const float* U_lstm = (const float*)d_in[24];
  const float* b_lstm = (const float*)d_in[25];
  const float* W_out  = (const float*)d_in[26];
  const float* b_out  = (const float*)d_in[27];

  char* ws = (char*)d_ws;
  size_t off = 0;
  auto alloc = [&](size_t bytes)->char*{
    char* p = ws + off; off += (bytes + 255) & ~(size_t)255; return p;
  };
  short* bah16          = (short*)alloc((size_t)B_*T_*U_*2);                    // 23.6 MB
  short* c1             = (short*)alloc((size_t)NSM_*H1_*W1_*K_*2);             // 172.8 MB
  short* c2m            = (short*)alloc((size_t)NSM_*H2_*W2_*K_*2);             // 157.4 MB
  short* cy             = (short*)alloc((size_t)NSY_*HY_*WY_*K_*2);             // 167.7 MB
  float* e              = (float*)alloc((size_t)B_*T_*4);
  float* aw             = (float*)alloc((size_t)B_*T_*4);
  float* sdec           = (float*)alloc(B_*U_*4);
  float* em_pre         = (float*)alloc(NSM_*64*4);
  float* ey_pre         = (float*)alloc(NSY_*64*4);
  float* m_att          = (float*)alloc(NSM_*4);
  float* y_att          = (float*)alloc(NSY_*4);
  float* ctx            = (float*)alloc(B_*DENC_*4);
  float* zbuf           = (float*)alloc(B_*1024*4);
  short* Wenc_bf        = (short*)alloc(DENC_*U_*2);                            // 64 KB

  float* out   = (float*)d_out;              // [16,1,64]
  float* h_new = out + 1024;                 // [16,256]
  float* c_new = h_new + 4096;               // [16,256]
  float* nw    = c_new + 4096;               // [16,5760]

  // fused setup: Wenc cvt (32 blk) + sdec (16) + em_pre (480) + ey_pre (40) + ctx (16)
  k_setup<<<584, 256, 0, stream>>>(W_enc, Wenc_bf, S_prev, W_dec, sdec,
                                   bm1, em_pre, by1, ey_pre, ctx);
  k_bah_att<<<(B_*T_)/64, 256, 0, stream>>>(h_enc, Wenc_bf, sdec,
                                            W_att1, W_att2, W_att3, bah16, e);
  k_softmax<<<B_, 256, 0, stream>>>(e, aw);
  k_conv1s<<<NSM_*2, 256, 0, stream>>>(bah16, conv1_k, conv1_b, c1);
  // fused conv2 + convy over c1 (year view [160][540][1000]), 2 row-strips
  k_convf<<<NSY_*12*2, 256, 0, stream>>>(c1, conv2_k, conv2_b, convy_k, convy_b, c2m, cy);
  // FLATM: K-step 64 -> nsteps=641, kchunks=81, spc=8 -> grid 2430
  k_gemm64m<<<81*30, 256, 0, stream>>>((const __hip_bfloat16*)c2m, Wm1, em_pre, NSM_, (long)FLATM_, 30, 8);
  k_month_head<<<NSY_, 64, 0, stream>>>(em_pre, Wm2, bm2, m_att);
  // FLATY: K-step 64 -> nsteps=8190, kchunks=512, spc=16 -> grid 1536
  k_gemm64m<<<512*3, 256, 0, stream>>>((const __hip_bfloat16*)cy, Wy1, ey_pre, NSY_, (long)FLATY_, 3, 16);
  k_year_head<<<B_, 64, 0, stream>>>(ey_pre, Wy2, by2, y_att);
  k_new_w<<<(B_*T_+255)/256, 256, 0, stream>>>(aw, m_att, y_att, nw);
  k_ctx<<<B_*64, 256, 0, stream>>>(nw, h_enc, ctx);
  k_lstm_z<<<B_*4, 256, 0, stream>>>(ctx, dec_input, S_prev, W_lstm, U_lstm, b_lstm, zbuf);
  k_gates<<<B_, 256, 0, stream>>>(zbuf, C_prev, h_new, c_new);
  k_out<<<B_, 64, 0, stream>>>(h_new, W_out, b_out, out);
}